// Round 8
// baseline (867.358 us; speedup 1.0000x reference)
//
#include <hip/hip_runtime.h>
#include <hip/hip_fp16.h>

#define CH 64
#define PSH 8            // 256 dsts per partition
#define PSZ 256
#define TILE 2048        // edges per part2 block
#define EPT 8            // edges per thread
#define CAP2 16          // ints per cell: [cnt][<=15 entries]; Poisson(5.24), spill backs it up
#define RANGE 12500      // outdeg-histogram bins per block (50 KB LDS)
#define SLICES 8
#define SPILLMAX 8192

// ---------------- pass 1: bin edges into per-(partition,tile) cells ----------
// Fixed-slot cells -> ZERO global atomics, no cross-block dependencies.
__global__ __launch_bounds__(256) void part2_kernel(const int* __restrict__ src,
                                                    const int* __restrict__ dst,
                                                    int* __restrict__ cells,
                                                    int* __restrict__ spill,
                                                    int* __restrict__ nspill,
                                                    int E, int P, int NT)
{
    __shared__ int hist[512];
    int tid = threadIdx.x;
    int t = blockIdx.x;
    int e0 = t * TILE + tid * EPT;
    int s[EPT], d[EPT];
    int nk = 0;
    if (e0 + EPT <= E) {
        const int4* sp = (const int4*)(src + e0);
        const int4* dp = (const int4*)(dst + e0);
        int4 a = sp[0], b = sp[1], c = dp[0], f = dp[1];
        s[0]=a.x; s[1]=a.y; s[2]=a.z; s[3]=a.w; s[4]=b.x; s[5]=b.y; s[6]=b.z; s[7]=b.w;
        d[0]=c.x; d[1]=c.y; d[2]=c.z; d[3]=c.w; d[4]=f.x; d[5]=f.y; d[6]=f.z; d[7]=f.w;
        nk = EPT;
    } else {
        for (int k = 0; e0 + k < E && k < EPT; ++k) { s[k] = src[e0+k]; d[k] = dst[e0+k]; nk++; }
    }
    for (int i = tid; i < P; i += 256) hist[i] = 0;
    __syncthreads();
    for (int k = 0; k < nk; ++k) {
        int p = d[k] >> PSH;
        int r = atomicAdd(&hist[p], 1);               // LDS atomic: rank within (tile,part)
        if (r < CAP2 - 1) {
            cells[((size_t)p * NT + t) * CAP2 + 1 + r] = (s[k] << PSH) | (d[k] & (PSZ - 1));
        } else {                                      // statistically ~1e-4/cell
            int sp2 = atomicAdd(nspill, 1);
            if (sp2 < SPILLMAX) { spill[2*sp2] = d[k]; spill[2*sp2+1] = s[k]; }
        }
    }
    __syncthreads();
    for (int i = tid; i < P; i += 256) {
        int c = hist[i];
        if (c > CAP2 - 1) c = CAP2 - 1;
        cells[((size_t)i * NT + t) * CAP2] = c;       // cnt written every launch (no memset)
    }
}

// ---------------- outdeg: privatized LDS histograms -> partials -------------
__global__ __launch_bounds__(256) void odeg_hist_kernel(const int* __restrict__ src,
                                                        int* __restrict__ partial,
                                                        int E, int N, int R)
{
    __shared__ int h[RANGE];
    int r  = blockIdx.x % R;
    int sl = blockIdx.x / R;
    int lo = r * RANGE;
    int hi = min(lo + RANGE, N);
    int span = hi - lo;
    for (int i = threadIdx.x; i < span; i += 256) h[i] = 0;
    __syncthreads();
    int per = (E + SLICES - 1) / SLICES;
    int sb = sl * per, se = min(sb + per, E);
    for (int e = sb + threadIdx.x; e < se; e += 256) {
        int sv = src[e];
        if (sv >= lo && sv < hi) atomicAdd(&h[sv - lo], 1);
    }
    __syncthreads();
    int* pp = partial + (size_t)blockIdx.x * RANGE;
    for (int i = threadIdx.x; i < span; i += 256) pp[i] = h[i];
}

__global__ __launch_bounds__(256) void odeg_reduce_kernel(const int* __restrict__ partial,
                                                          int* __restrict__ outdeg,
                                                          int N, int R)
{
    int n = blockIdx.x * 256 + threadIdx.x;
    if (n >= N) return;
    int r = n / RANGE, off = n - r * RANGE;
    int s = 0;
    for (int sl = 0; sl < SLICES; ++sl)
        s += partial[(size_t)(sl * R + r) * RANGE + off];
    outdeg[n] = s;
}

// ---------------- prescale: xh[n] = rsqrt(outdeg[n]) * x[n]  (fp16) ---------
__global__ __launch_bounds__(256) void prescale_kernel(const float* __restrict__ x,
                                                       const int* __restrict__ outdeg,
                                                       __half* __restrict__ xh, int N)
{
    int g = blockIdx.x * blockDim.x + threadIdx.x;
    int total = N * (CH / 8);
    if (g >= total) return;
    int node = g >> 3, sub = g & 7;
    int od = outdeg[node];
    float ns = (od > 0) ? rsqrtf((float)od) : 0.0f;
    const float4* xp = (const float4*)(x + (size_t)node * CH + sub * 8);
    float4 a = xp[0], b = xp[1];
    __half2 h0 = __floats2half2_rn(a.x * ns, a.y * ns);
    __half2 h1 = __floats2half2_rn(a.z * ns, a.w * ns);
    __half2 h2 = __floats2half2_rn(b.x * ns, b.y * ns);
    __half2 h3 = __floats2half2_rn(b.z * ns, b.w * ns);
    uint4 u;
    u.x = (unsigned)__half_as_ushort(h0.x) | ((unsigned)__half_as_ushort(h0.y) << 16);
    u.y = (unsigned)__half_as_ushort(h1.x) | ((unsigned)__half_as_ushort(h1.y) << 16);
    u.z = (unsigned)__half_as_ushort(h2.x) | ((unsigned)__half_as_ushort(h2.y) << 16);
    u.w = (unsigned)__half_as_ushort(h3.x) | ((unsigned)__half_as_ushort(h3.y) << 16);
    *(uint4*)(xh + (size_t)node * CH + sub * 8) = u;
}

// ---------------- pass 2: aggregate; 32-lane group per edge -----------------
// block = (partition p, channel-half); LDS acc[256 dst][32 ch] fp32.
// Per edge: 1 shfl broadcast + 64B coalesced gather + 1 conflict-free LDS atomic/lane.
__global__ __launch_bounds__(256) void agg2_kernel(const __half* __restrict__ xh,
                                                   const int* __restrict__ cells,
                                                   const int* __restrict__ spill,
                                                   const int* __restrict__ nspill,
                                                   __half* __restrict__ aggh,
                                                   int N, int NT)
{
    __shared__ float acc[PSZ * 32];
    __shared__ int cnt[PSZ];
    int bid = blockIdx.x;
    int half = bid & 1;
    int p = bid >> 1;
    int tid = threadIdx.x;
    int g = tid >> 5;          // 32-lane group id (8 per block)
    int lane = tid & 31;
    for (int i = tid; i < PSZ * 32; i += 256) acc[i] = 0.0f;
    for (int i = tid; i < PSZ; i += 256) cnt[i] = 0;
    __syncthreads();
    const int chbase = half * 32;
    for (int t = g; t < NT; t += 8) {
        const int* cb = cells + ((size_t)p * NT + t) * CAP2;
        int v = cb[lane & (CAP2 - 1)];            // one 64B line, all lanes
        int c = __shfl(v, 0, 32);
        for (int i = 1; i <= c; ++i) {
            int e = __shfl(v, i, 32);
            int sv = e >> PSH;
            int dl = e & (PSZ - 1);
            float f = __half2float(xh[(size_t)sv * CH + chbase + lane]);
            atomicAdd(&acc[dl * 32 + lane], f);   // bank = lane: conflict-free
            if (lane == 0) atomicAdd(&cnt[dl], 1);
        }
    }
    if (g == 0) {              // cold spill sweep (0 or a handful of entries)
        int ns = *nspill;
        if (ns > SPILLMAX) ns = SPILLMAX;
        for (int i = 0; i < ns; ++i) {
            int dfull = spill[2*i];
            if ((dfull >> PSH) == p) {
                int sv = spill[2*i+1];
                int dl = dfull & (PSZ - 1);
                float f = __half2float(xh[(size_t)sv * CH + chbase + lane]);
                atomicAdd(&acc[dl * 32 + lane], f);
                if (lane == 0) atomicAdd(&cnt[dl], 1);
            }
        }
    }
    __syncthreads();
    for (int i = tid; i < PSZ * 16; i += 256) {   // 16 half2 per dst for this half
        int dl = i >> 4;
        int c2 = (i & 15) * 2;
        int node = (p << PSH) + dl;
        if (node >= N) continue;
        int c = cnt[dl];
        float nd = (c > 0) ? rsqrtf((float)c) : 0.0f;
        float fx = acc[dl * 32 + c2]     * nd;
        float fy = acc[dl * 32 + c2 + 1] * nd;
        *(__half2*)(aggh + (size_t)node * CH + chbase + c2) = __floats2half2_rn(fx, fy);
    }
}

// ---------------- out = aggh @ W + bias  (row per thread, W scalarized) -----
__global__ __launch_bounds__(256) void gemm_out_kernel(const __half* __restrict__ aggh,
                                                       const float* __restrict__ W,
                                                       const float* __restrict__ bias,
                                                       float* __restrict__ out, int N)
{
    int row = blockIdx.x * blockDim.x + threadIdx.x;
    if (row >= N) return;
    float xr[CH];
    const __half2* xp = (const __half2*)(aggh + (size_t)row * CH);
    #pragma unroll
    for (int j = 0; j < CH / 2; ++j) {
        float2 f = __half22float2(xp[j]);
        xr[2 * j + 0] = f.x;
        xr[2 * j + 1] = f.y;
    }
    float* op = out + (size_t)row * CH;
    for (int c0 = 0; c0 < CH; c0 += 16) {
        float acc[16];
        #pragma unroll
        for (int q = 0; q < 16; ++q) acc[q] = 0.0f;
        #pragma unroll 8
        for (int k = 0; k < CH; ++k) {
            const float xk = xr[k];
            #pragma unroll
            for (int q = 0; q < 4; ++q) {
                float4 w = *(const float4*)(W + k * CH + c0 + q * 4);  // wave-uniform -> s_load
                acc[q * 4 + 0] += xk * w.x;
                acc[q * 4 + 1] += xk * w.y;
                acc[q * 4 + 2] += xk * w.z;
                acc[q * 4 + 3] += xk * w.w;
            }
        }
        #pragma unroll
        for (int q = 0; q < 4; ++q) {
            float4 b = *(const float4*)(bias + c0 + q * 4);
            float4 o;
            o.x = acc[q * 4 + 0] + b.x;
            o.y = acc[q * 4 + 1] + b.y;
            o.z = acc[q * 4 + 2] + b.z;
            o.w = acc[q * 4 + 3] + b.w;
            *(float4*)(op + c0 + q * 4) = o;
        }
    }
}

extern "C" void kernel_launch(void* const* d_in, const int* in_sizes, int n_in,
                              void* d_out, int out_size, void* d_ws, size_t ws_size,
                              hipStream_t stream)
{
    const float* x    = (const float*)d_in[0];
    const int*   edge = (const int*)d_in[1];
    const float* W    = (const float*)d_in[2];
    const float* bias = (const float*)d_in[3];
    float* out = (float*)d_out;

    int N = in_sizes[0] / CH;   // 100000
    int E = in_sizes[1] / 2;    // 1280000
    const int* src = edge;
    const int* dst = edge + E;
    int P  = (N + PSZ - 1) >> PSH;         // 391
    int NT = (E + TILE - 1) / TILE;        // 625
    int R  = (N + RANGE - 1) / RANGE;      // 8

    // workspace (ints 4B):
    // [nspill 64][spill 2*SPILLMAX][cells P*NT*CAP2 ~15.6MB][partial SLICES*R*RANGE ~3.2MB]
    // [outdeg N][align][xh N*CH halves][align][aggh N*CH halves]   (~45 MB)
    int* nspill  = (int*)d_ws;
    int* spill   = nspill + 64;
    int* cells   = spill + 2 * SPILLMAX;
    int* partial = cells + (size_t)P * NT * CAP2;
    int* outdeg  = partial + (size_t)SLICES * R * RANGE;
    size_t xoff = (((char*)(outdeg + N) - (char*)d_ws) + 255) & ~(size_t)255;
    __half* xh = (__half*)((char*)d_ws + xoff);
    size_t aoff = ((xoff + (size_t)N * CH * sizeof(__half)) + 255) & ~(size_t)255;
    __half* aggh = (__half*)((char*)d_ws + aoff);

    hipMemsetAsync(nspill, 0, 64 * sizeof(int), stream);

    part2_kernel<<<NT, 256, 0, stream>>>(src, dst, cells, spill, nspill, E, P, NT);
    odeg_hist_kernel<<<R * SLICES, 256, 0, stream>>>(src, partial, E, N, R);
    odeg_reduce_kernel<<<(N + 255) / 256, 256, 0, stream>>>(partial, outdeg, N, R);
    prescale_kernel<<<(N * (CH / 8) + 255) / 256, 256, 0, stream>>>(x, outdeg, xh, N);
    agg2_kernel<<<2 * P, 256, 0, stream>>>(xh, cells, spill, nspill, aggh, N, NT);
    gemm_out_kernel<<<(N + 255) / 256, 256, 0, stream>>>(aggh, W, bias, out, N);
}

// Round 9
// 279.714 us; speedup vs baseline: 3.1009x; 3.1009x over previous
//
#include <hip/hip_runtime.h>
#include <hip/hip_fp16.h>

#define CH 64
#define CAP 40        // bucket capacity; indeg ~ Poisson(12.8), P(>=40) ~ 7e-10
#define SPILLMAX 4096
#define RANGE 12500   // outdeg-histogram bins per block (50 KB LDS)
#define SLICES 16

// ---------------- outdeg: privatized LDS histograms (zero global atomics) ---
__global__ __launch_bounds__(256) void hist_kernel(const int* __restrict__ src,
                                                   int* __restrict__ partial,
                                                   int E, int N, int R)
{
    __shared__ int h[RANGE];
    int r  = blockIdx.x % R;
    int sl = blockIdx.x / R;
    int lo = r * RANGE;
    int hi = min(lo + RANGE, N);
    int span = hi - lo;
    for (int i = threadIdx.x; i < span; i += 256) h[i] = 0;
    __syncthreads();
    int per = (E + SLICES - 1) / SLICES;
    int sb = sl * per, se = min(sb + per, E);
    for (int e = sb + threadIdx.x; e < se; e += 256) {
        int sv = src[e];
        if (sv >= lo && sv < hi) atomicAdd(&h[sv - lo], 1);
    }
    __syncthreads();
    int* pp = partial + (size_t)blockIdx.x * RANGE;
    for (int i = threadIdx.x; i < span; i += 256) pp[i] = h[i];
}

__global__ __launch_bounds__(256) void odeg_reduce_kernel(const int* __restrict__ partial,
                                                          int* __restrict__ outdeg,
                                                          int N, int R)
{
    int n = blockIdx.x * 256 + threadIdx.x;
    if (n >= N) return;
    int r = n / RANGE, off = n - r * RANGE;
    int s = 0;
    for (int sl = 0; sl < SLICES; ++sl)
        s += partial[(size_t)(sl * R + r) * RANGE + off];
    outdeg[n] = s;
}

// ---------------- build: bucket fill by dst; cnt doubles as indeg -----------
// Exactly 1 random atomic + 1 scattered 4B write per edge.
__global__ __launch_bounds__(256) void build_kernel(const int* __restrict__ src,
                                                    const int* __restrict__ dst,
                                                    int* __restrict__ cnt,
                                                    int* __restrict__ bucket,
                                                    int* __restrict__ spill,
                                                    int* __restrict__ nspill, int E)
{
    int e = blockIdx.x * blockDim.x + threadIdx.x;
    if (e >= E) return;
    int s = src[e];
    int d = dst[e];
    int pos = atomicAdd(&cnt[d], 1);
    if (pos < CAP) {
        bucket[(size_t)d * CAP + pos] = s;
    } else {                       // statistically never on this data
        int sp = atomicAdd(nspill, 1);
        if (sp < SPILLMAX) { spill[2 * sp] = d; spill[2 * sp + 1] = s; }
    }
}

// ---------------- prescale: xh[n] = rsqrt(outdeg[n]) * x[n]  (fp16) ---------
__global__ __launch_bounds__(256) void prescale_kernel(const float* __restrict__ x,
                                                       const int* __restrict__ outdeg,
                                                       __half* __restrict__ xh, int N)
{
    int g = blockIdx.x * blockDim.x + threadIdx.x;   // one thread per 8 channels
    int total = N * (CH / 8);
    if (g >= total) return;
    int node = g >> 3, sub = g & 7;
    int od = outdeg[node];
    float ns = (od > 0) ? rsqrtf((float)od) : 0.0f;
    const float4* xp = (const float4*)(x + (size_t)node * CH + sub * 8);
    float4 a = xp[0], b = xp[1];
    __half2 h0 = __floats2half2_rn(a.x * ns, a.y * ns);
    __half2 h1 = __floats2half2_rn(a.z * ns, a.w * ns);
    __half2 h2 = __floats2half2_rn(b.x * ns, b.y * ns);
    __half2 h3 = __floats2half2_rn(b.z * ns, b.w * ns);
    uint4 u;
    u.x = (unsigned)__half_as_ushort(h0.x) | ((unsigned)__half_as_ushort(h0.y) << 16);
    u.y = (unsigned)__half_as_ushort(h1.x) | ((unsigned)__half_as_ushort(h1.y) << 16);
    u.z = (unsigned)__half_as_ushort(h2.x) | ((unsigned)__half_as_ushort(h2.y) << 16);
    u.w = (unsigned)__half_as_ushort(h3.x) | ((unsigned)__half_as_ushort(h3.y) << 16);
    *(uint4*)(xh + (size_t)node * CH + sub * 8) = u;
}

// ---------------- aggregate: half-wave (32 lanes) per node, half2 per lane --
// aggh[n] = fp16( rsqrt(cnt_n) * sum_{e in bucket(n)} xh[src_e] )
__global__ __launch_bounds__(256) void agg_kernel(const __half* __restrict__ xh,
                                                  const int* __restrict__ bucket,
                                                  const int* __restrict__ cnt,
                                                  const int* __restrict__ spill,
                                                  const int* __restrict__ nspill,
                                                  __half* __restrict__ aggh, int N)
{
    int node = (blockIdx.x * blockDim.x + threadIdx.x) >> 5;
    int sl = threadIdx.x & 31;
    if (node >= N) return;
    int c = cnt[node];
    int m = (c < CAP) ? c : CAP;
    const int* bp = bucket + (size_t)node * CAP;
    float ax0 = 0, ay0 = 0, ax1 = 0, ay1 = 0, ax2 = 0, ay2 = 0, ax3 = 0, ay3 = 0;
    int j = 0;
    for (; j + 4 <= m; j += 4) {
        int s0 = bp[j + 0], s1 = bp[j + 1], s2 = bp[j + 2], s3 = bp[j + 3];
        float2 f0 = __half22float2(*(const __half2*)(xh + (size_t)s0 * CH + sl * 2));
        float2 f1 = __half22float2(*(const __half2*)(xh + (size_t)s1 * CH + sl * 2));
        float2 f2 = __half22float2(*(const __half2*)(xh + (size_t)s2 * CH + sl * 2));
        float2 f3 = __half22float2(*(const __half2*)(xh + (size_t)s3 * CH + sl * 2));
        ax0 += f0.x; ay0 += f0.y;
        ax1 += f1.x; ay1 += f1.y;
        ax2 += f2.x; ay2 += f2.y;
        ax3 += f3.x; ay3 += f3.y;
    }
    for (; j < m; ++j) {
        float2 f = __half22float2(*(const __half2*)(xh + (size_t)bp[j] * CH + sl * 2));
        ax0 += f.x; ay0 += f.y;
    }
    if (c > CAP) {   // cold spill sweep (keeps any-input correctness)
        int ns = *nspill;
        if (ns > SPILLMAX) ns = SPILLMAX;
        for (int i = 0; i < ns; ++i) {
            if (spill[2 * i] == node) {
                float2 f = __half22float2(*(const __half2*)(xh + (size_t)spill[2 * i + 1] * CH + sl * 2));
                ax0 += f.x; ay0 += f.y;
            }
        }
    }
    float nd = (c > 0) ? rsqrtf((float)c) : 0.0f;
    float rx = ((ax0 + ax1) + (ax2 + ax3)) * nd;
    float ry = ((ay0 + ay1) + (ay2 + ay3)) * nd;
    *(__half2*)(aggh + (size_t)node * CH + sl * 2) = __floats2half2_rn(rx, ry);
}

// ---------------- out = aggh @ W + bias  (row per thread, W scalarized) -----
__global__ __launch_bounds__(256) void gemm_out_kernel(const __half* __restrict__ aggh,
                                                       const float* __restrict__ W,
                                                       const float* __restrict__ bias,
                                                       float* __restrict__ out, int N)
{
    int row = blockIdx.x * blockDim.x + threadIdx.x;
    if (row >= N) return;
    float xr[CH];
    const __half2* xp = (const __half2*)(aggh + (size_t)row * CH);
    #pragma unroll
    for (int j = 0; j < CH / 2; ++j) {
        float2 f = __half22float2(xp[j]);
        xr[2 * j + 0] = f.x;
        xr[2 * j + 1] = f.y;
    }
    float* op = out + (size_t)row * CH;
    for (int c0 = 0; c0 < CH; c0 += 16) {
        float acc[16];
        #pragma unroll
        for (int q = 0; q < 16; ++q) acc[q] = 0.0f;
        #pragma unroll 8
        for (int k = 0; k < CH; ++k) {
            const float xk = xr[k];
            #pragma unroll
            for (int q = 0; q < 4; ++q) {
                float4 w = *(const float4*)(W + k * CH + c0 + q * 4);  // wave-uniform -> s_load
                acc[q * 4 + 0] += xk * w.x;
                acc[q * 4 + 1] += xk * w.y;
                acc[q * 4 + 2] += xk * w.z;
                acc[q * 4 + 3] += xk * w.w;
            }
        }
        #pragma unroll
        for (int q = 0; q < 4; ++q) {
            float4 b = *(const float4*)(bias + c0 + q * 4);
            float4 o;
            o.x = acc[q * 4 + 0] + b.x;
            o.y = acc[q * 4 + 1] + b.y;
            o.z = acc[q * 4 + 2] + b.z;
            o.w = acc[q * 4 + 3] + b.w;
            *(float4*)(op + c0 + q * 4) = o;
        }
    }
}

extern "C" void kernel_launch(void* const* d_in, const int* in_sizes, int n_in,
                              void* d_out, int out_size, void* d_ws, size_t ws_size,
                              hipStream_t stream)
{
    const float* x    = (const float*)d_in[0];
    const int*   edge = (const int*)d_in[1];
    const float* W    = (const float*)d_in[2];
    const float* bias = (const float*)d_in[3];
    float* out = (float*)d_out;

    int N = in_sizes[0] / CH;   // 100000
    int E = in_sizes[1] / 2;    // 1280000
    const int* src = edge;
    const int* dst = edge + E;
    int R = (N + RANGE - 1) / RANGE;   // 8

    // workspace (ints 4B):
    // [cnt N][nspill 64][spill 2*SPILLMAX][outdeg N][partial SLICES*R*RANGE ~6.4MB]
    // [bucket N*CAP ~16MB][align][xh N*CH halves][align][aggh N*CH halves]  (~49 MB)
    int* cnt     = (int*)d_ws;
    int* nspill  = cnt + N;
    int* spill   = nspill + 64;
    int* outdeg  = spill + 2 * SPILLMAX;
    int* partial = outdeg + N;
    int* bucket  = partial + (size_t)SLICES * R * RANGE;
    size_t xoff = (((char*)(bucket + (size_t)N * CAP) - (char*)d_ws) + 255) & ~(size_t)255;
    __half* xh = (__half*)((char*)d_ws + xoff);
    size_t aoff = ((xoff + (size_t)N * CH * sizeof(__half)) + 255) & ~(size_t)255;
    __half* aggh = (__half*)((char*)d_ws + aoff);

    // zero cnt + nspill (contiguous)
    hipMemsetAsync(cnt, 0, ((size_t)N + 64) * sizeof(int), stream);

    hist_kernel<<<R * SLICES, 256, 0, stream>>>(src, partial, E, N, R);
    odeg_reduce_kernel<<<(N + 255) / 256, 256, 0, stream>>>(partial, outdeg, N, R);
    build_kernel<<<(E + 255) / 256, 256, 0, stream>>>(src, dst, cnt, bucket, spill, nspill, E);
    prescale_kernel<<<(N * (CH / 8) + 255) / 256, 256, 0, stream>>>(x, outdeg, xh, N);
    agg_kernel<<<((size_t)N * 32 + 255) / 256, 256, 0, stream>>>(xh, bucket, cnt, spill,
                                                                 nspill, aggh, N);
    gemm_out_kernel<<<(N + 255) / 256, 256, 0, stream>>>(aggh, W, bias, out, N);
}

// Round 10
// 200.502 us; speedup vs baseline: 4.3259x; 1.3951x over previous
//
#include <hip/hip_runtime.h>
#include <hip/hip_fp16.h>

#define CH 64
#define CAP 40        // bucket capacity; indeg ~ Poisson(12.8), P(>=40) ~ 7e-10
#define SPILLMAX 4096
#define RANGE 12500   // outdeg-histogram bins per block (50 KB LDS)
#define SLICES 64     // 8 ranges x 64 slices = 512 blocks (2 per CU)

// ---------------- outdeg: privatized LDS histograms (zero global atomics) ---
__global__ __launch_bounds__(256) void hist_kernel(const int* __restrict__ src,
                                                   int* __restrict__ partial,
                                                   int E, int N, int R)
{
    __shared__ int h[RANGE];
    int r  = blockIdx.x % R;
    int sl = blockIdx.x / R;
    int lo = r * RANGE;
    int hi = min(lo + RANGE, N);
    int span = hi - lo;
    for (int i = threadIdx.x; i < span; i += 256) h[i] = 0;
    __syncthreads();
    int per = (E + SLICES - 1) / SLICES;       // 20000
    int sb = sl * per, se = min(sb + per, E);
    // int4-vectorized, independent iterations -> loads pipeline
    for (int e = sb + threadIdx.x * 4; e < se; e += 256 * 4) {
        if (e + 4 <= se) {
            int4 v = *(const int4*)(src + e);
            if (v.x >= lo && v.x < hi) atomicAdd(&h[v.x - lo], 1);
            if (v.y >= lo && v.y < hi) atomicAdd(&h[v.y - lo], 1);
            if (v.z >= lo && v.z < hi) atomicAdd(&h[v.z - lo], 1);
            if (v.w >= lo && v.w < hi) atomicAdd(&h[v.w - lo], 1);
        } else {
            for (int k = e; k < se; ++k) {
                int sv = src[k];
                if (sv >= lo && sv < hi) atomicAdd(&h[sv - lo], 1);
            }
        }
    }
    __syncthreads();
    int* pp = partial + (size_t)blockIdx.x * RANGE;
    for (int i = threadIdx.x; i < span; i += 256) pp[i] = h[i];
}

__global__ __launch_bounds__(256) void odeg_reduce_kernel(const int* __restrict__ partial,
                                                          int* __restrict__ outdeg,
                                                          int N, int R)
{
    int n = blockIdx.x * 256 + threadIdx.x;
    if (n >= N) return;
    int r = n / RANGE, off = n - r * RANGE;
    int s = 0;
    #pragma unroll 8
    for (int sl = 0; sl < SLICES; ++sl)
        s += partial[(size_t)(sl * R + r) * RANGE + off];
    outdeg[n] = s;
}

// ---------------- build: bucket fill by dst; cnt doubles as indeg -----------
// Exactly 1 random atomic + 1 scattered 4B write per edge.
__global__ __launch_bounds__(256) void build_kernel(const int* __restrict__ src,
                                                    const int* __restrict__ dst,
                                                    int* __restrict__ cnt,
                                                    int* __restrict__ bucket,
                                                    int* __restrict__ spill,
                                                    int* __restrict__ nspill, int E)
{
    int e = blockIdx.x * blockDim.x + threadIdx.x;
    if (e >= E) return;
    int s = src[e];
    int d = dst[e];
    int pos = atomicAdd(&cnt[d], 1);
    if (pos < CAP) {
        bucket[(size_t)d * CAP + pos] = s;
    } else {                       // statistically never on this data
        int sp = atomicAdd(nspill, 1);
        if (sp < SPILLMAX) { spill[2 * sp] = d; spill[2 * sp + 1] = s; }
    }
}

// ---------------- prescale: xh[n] = rsqrt(outdeg[n]) * x[n]  (fp16) ---------
__global__ __launch_bounds__(256) void prescale_kernel(const float* __restrict__ x,
                                                       const int* __restrict__ outdeg,
                                                       __half* __restrict__ xh, int N)
{
    int g = blockIdx.x * blockDim.x + threadIdx.x;   // one thread per 8 channels
    int total = N * (CH / 8);
    if (g >= total) return;
    int node = g >> 3, sub = g & 7;
    int od = outdeg[node];
    float ns = (od > 0) ? rsqrtf((float)od) : 0.0f;
    const float4* xp = (const float4*)(x + (size_t)node * CH + sub * 8);
    float4 a = xp[0], b = xp[1];
    __half2 h0 = __floats2half2_rn(a.x * ns, a.y * ns);
    __half2 h1 = __floats2half2_rn(a.z * ns, a.w * ns);
    __half2 h2 = __floats2half2_rn(b.x * ns, b.y * ns);
    __half2 h3 = __floats2half2_rn(b.z * ns, b.w * ns);
    uint4 u;
    u.x = (unsigned)__half_as_ushort(h0.x) | ((unsigned)__half_as_ushort(h0.y) << 16);
    u.y = (unsigned)__half_as_ushort(h1.x) | ((unsigned)__half_as_ushort(h1.y) << 16);
    u.z = (unsigned)__half_as_ushort(h2.x) | ((unsigned)__half_as_ushort(h2.y) << 16);
    u.w = (unsigned)__half_as_ushort(h3.x) | ((unsigned)__half_as_ushort(h3.y) << 16);
    *(uint4*)(xh + (size_t)node * CH + sub * 8) = u;
}

// ---------------- aggregate: half-wave (32 lanes) per node, half2 per lane --
// aggh[n] = fp16( rsqrt(cnt_n) * sum_{e in bucket(n)} xh[src_e] )
__global__ __launch_bounds__(256) void agg_kernel(const __half* __restrict__ xh,
                                                  const int* __restrict__ bucket,
                                                  const int* __restrict__ cnt,
                                                  const int* __restrict__ spill,
                                                  const int* __restrict__ nspill,
                                                  __half* __restrict__ aggh, int N)
{
    int node = (blockIdx.x * blockDim.x + threadIdx.x) >> 5;
    int sl = threadIdx.x & 31;
    if (node >= N) return;
    int c = cnt[node];
    int m = (c < CAP) ? c : CAP;
    const int* bp = bucket + (size_t)node * CAP;
    float ax0 = 0, ay0 = 0, ax1 = 0, ay1 = 0, ax2 = 0, ay2 = 0, ax3 = 0, ay3 = 0;
    int j = 0;
    for (; j + 4 <= m; j += 4) {
        int s0 = bp[j + 0], s1 = bp[j + 1], s2 = bp[j + 2], s3 = bp[j + 3];
        float2 f0 = __half22float2(*(const __half2*)(xh + (size_t)s0 * CH + sl * 2));
        float2 f1 = __half22float2(*(const __half2*)(xh + (size_t)s1 * CH + sl * 2));
        float2 f2 = __half22float2(*(const __half2*)(xh + (size_t)s2 * CH + sl * 2));
        float2 f3 = __half22float2(*(const __half2*)(xh + (size_t)s3 * CH + sl * 2));
        ax0 += f0.x; ay0 += f0.y;
        ax1 += f1.x; ay1 += f1.y;
        ax2 += f2.x; ay2 += f2.y;
        ax3 += f3.x; ay3 += f3.y;
    }
    for (; j < m; ++j) {
        float2 f = __half22float2(*(const __half2*)(xh + (size_t)bp[j] * CH + sl * 2));
        ax0 += f.x; ay0 += f.y;
    }
    if (c > CAP) {   // cold spill sweep (keeps any-input correctness)
        int ns = *nspill;
        if (ns > SPILLMAX) ns = SPILLMAX;
        for (int i = 0; i < ns; ++i) {
            if (spill[2 * i] == node) {
                float2 f = __half22float2(*(const __half2*)(xh + (size_t)spill[2 * i + 1] * CH + sl * 2));
                ax0 += f.x; ay0 += f.y;
            }
        }
    }
    float nd = (c > 0) ? rsqrtf((float)c) : 0.0f;
    float rx = ((ax0 + ax1) + (ax2 + ax3)) * nd;
    float ry = ((ay0 + ay1) + (ay2 + ay3)) * nd;
    *(__half2*)(aggh + (size_t)node * CH + sl * 2) = __floats2half2_rn(rx, ry);
}

// ---------------- out = aggh @ W + bias  (row per thread, W scalarized) -----
__global__ __launch_bounds__(256) void gemm_out_kernel(const __half* __restrict__ aggh,
                                                       const float* __restrict__ W,
                                                       const float* __restrict__ bias,
                                                       float* __restrict__ out, int N)
{
    int row = blockIdx.x * blockDim.x + threadIdx.x;
    if (row >= N) return;
    float xr[CH];
    const __half2* xp = (const __half2*)(aggh + (size_t)row * CH);
    #pragma unroll
    for (int j = 0; j < CH / 2; ++j) {
        float2 f = __half22float2(xp[j]);
        xr[2 * j + 0] = f.x;
        xr[2 * j + 1] = f.y;
    }
    float* op = out + (size_t)row * CH;
    for (int c0 = 0; c0 < CH; c0 += 16) {
        float acc[16];
        #pragma unroll
        for (int q = 0; q < 16; ++q) acc[q] = 0.0f;
        #pragma unroll 8
        for (int k = 0; k < CH; ++k) {
            const float xk = xr[k];
            #pragma unroll
            for (int q = 0; q < 4; ++q) {
                float4 w = *(const float4*)(W + k * CH + c0 + q * 4);  // wave-uniform -> s_load
                acc[q * 4 + 0] += xk * w.x;
                acc[q * 4 + 1] += xk * w.y;
                acc[q * 4 + 2] += xk * w.z;
                acc[q * 4 + 3] += xk * w.w;
            }
        }
        #pragma unroll
        for (int q = 0; q < 4; ++q) {
            float4 b = *(const float4*)(bias + c0 + q * 4);
            float4 o;
            o.x = acc[q * 4 + 0] + b.x;
            o.y = acc[q * 4 + 1] + b.y;
            o.z = acc[q * 4 + 2] + b.z;
            o.w = acc[q * 4 + 3] + b.w;
            *(float4*)(op + c0 + q * 4) = o;
        }
    }
}

extern "C" void kernel_launch(void* const* d_in, const int* in_sizes, int n_in,
                              void* d_out, int out_size, void* d_ws, size_t ws_size,
                              hipStream_t stream)
{
    const float* x    = (const float*)d_in[0];
    const int*   edge = (const int*)d_in[1];
    const float* W    = (const float*)d_in[2];
    const float* bias = (const float*)d_in[3];
    float* out = (float*)d_out;

    int N = in_sizes[0] / CH;   // 100000
    int E = in_sizes[1] / 2;    // 1280000
    const int* src = edge;
    const int* dst = edge + E;
    int R = (N + RANGE - 1) / RANGE;   // 8

    // workspace (ints 4B):
    // [cnt N][nspill 64][spill 2*SPILLMAX][outdeg N][partial SLICES*R*RANGE ~25.6MB]
    // [bucket N*CAP ~16MB][align][xh N*CH halves][align][aggh N*CH halves]  (~68 MB)
    int* cnt     = (int*)d_ws;
    int* nspill  = cnt + N;
    int* spill   = nspill + 64;
    int* outdeg  = spill + 2 * SPILLMAX;
    int* partial = outdeg + N;
    int* bucket  = partial + (size_t)SLICES * R * RANGE;
    size_t xoff = (((char*)(bucket + (size_t)N * CAP) - (char*)d_ws) + 255) & ~(size_t)255;
    __half* xh = (__half*)((char*)d_ws + xoff);
    size_t aoff = ((xoff + (size_t)N * CH * sizeof(__half)) + 255) & ~(size_t)255;
    __half* aggh = (__half*)((char*)d_ws + aoff);

    // zero cnt + nspill (contiguous)
    hipMemsetAsync(cnt, 0, ((size_t)N + 64) * sizeof(int), stream);

    hist_kernel<<<R * SLICES, 256, 0, stream>>>(src, partial, E, N, R);
    odeg_reduce_kernel<<<(N + 255) / 256, 256, 0, stream>>>(partial, outdeg, N, R);
    build_kernel<<<(E + 255) / 256, 256, 0, stream>>>(src, dst, cnt, bucket, spill, nspill, E);
    prescale_kernel<<<(N * (CH / 8) + 255) / 256, 256, 0, stream>>>(x, outdeg, xh, N);
    agg_kernel<<<((size_t)N * 32 + 255) / 256, 256, 0, stream>>>(xh, bucket, cnt, spill,
                                                                 nspill, aggh, N);
    gemm_out_kernel<<<(N + 255) / 256, 256, 0, stream>>>(aggh, W, bias, out, N);
}

// Round 11
// 140.846 us; speedup vs baseline: 6.1582x; 1.4236x over previous
//
#include <hip/hip_runtime.h>
#include <hip/hip_fp16.h>

#define CH 64
#define CAP 40        // per-node bucket capacity; indeg ~ Poisson(12.8), P(>=40) ~ 7e-10
#define SPILLMAX 4096
#define RANGE 12500   // outdeg-histogram bins per block (50 KB LDS)
#define SLICES 64     // 8 ranges x 64 slices = 512 blocks
#define TILE 2048     // edges per binA/binC block
#define EPT 8         // edges per thread (256 * 8 = 2048)
#define BSH 9         // 512 dsts per radix bucket
#define BKT 512

// ---------------- outdeg: privatized LDS histograms (zero global atomics) ---
__global__ __launch_bounds__(256) void hist_kernel(const int* __restrict__ src,
                                                   int* __restrict__ partial,
                                                   int E, int N, int R)
{
    __shared__ int h[RANGE];
    int r  = blockIdx.x % R;
    int sl = blockIdx.x / R;
    int lo = r * RANGE;
    int hi = min(lo + RANGE, N);
    int span = hi - lo;
    for (int i = threadIdx.x; i < span; i += 256) h[i] = 0;
    __syncthreads();
    int per = (E + SLICES - 1) / SLICES;
    int sb = sl * per, se = min(sb + per, E);
    for (int e = sb + threadIdx.x * 4; e < se; e += 256 * 4) {
        if (e + 4 <= se) {
            int4 v = *(const int4*)(src + e);
            if (v.x >= lo && v.x < hi) atomicAdd(&h[v.x - lo], 1);
            if (v.y >= lo && v.y < hi) atomicAdd(&h[v.y - lo], 1);
            if (v.z >= lo && v.z < hi) atomicAdd(&h[v.z - lo], 1);
            if (v.w >= lo && v.w < hi) atomicAdd(&h[v.w - lo], 1);
        } else {
            for (int k = e; k < se; ++k) {
                int sv = src[k];
                if (sv >= lo && sv < hi) atomicAdd(&h[sv - lo], 1);
            }
        }
    }
    __syncthreads();
    int* pp = partial + (size_t)blockIdx.x * RANGE;
    for (int i = threadIdx.x; i < span; i += 256) pp[i] = h[i];
}

__global__ __launch_bounds__(256) void odeg_reduce_kernel(const int* __restrict__ partial,
                                                          int* __restrict__ outdeg,
                                                          int N, int R)
{
    int n = blockIdx.x * 256 + threadIdx.x;
    if (n >= N) return;
    int r = n / RANGE, off = n - r * RANGE;
    int s = 0;
    #pragma unroll 8
    for (int sl = 0; sl < SLICES; ++sl)
        s += partial[(size_t)(sl * R + r) * RANGE + off];
    outdeg[n] = s;
}

// ---------------- prescale: xh[n] = rsqrt(outdeg[n]) * x[n]  (fp16) ---------
__global__ __launch_bounds__(256) void prescale_kernel(const float* __restrict__ x,
                                                       const int* __restrict__ outdeg,
                                                       __half* __restrict__ xh, int N)
{
    int g = blockIdx.x * blockDim.x + threadIdx.x;
    int total = N * (CH / 8);
    if (g >= total) return;
    int node = g >> 3, sub = g & 7;
    int od = outdeg[node];
    float ns = (od > 0) ? rsqrtf((float)od) : 0.0f;
    const float4* xp = (const float4*)(x + (size_t)node * CH + sub * 8);
    float4 a = xp[0], b = xp[1];
    __half2 h0 = __floats2half2_rn(a.x * ns, a.y * ns);
    __half2 h1 = __floats2half2_rn(a.z * ns, a.w * ns);
    __half2 h2 = __floats2half2_rn(b.x * ns, b.y * ns);
    __half2 h3 = __floats2half2_rn(b.z * ns, b.w * ns);
    uint4 u;
    u.x = (unsigned)__half_as_ushort(h0.x) | ((unsigned)__half_as_ushort(h0.y) << 16);
    u.y = (unsigned)__half_as_ushort(h1.x) | ((unsigned)__half_as_ushort(h1.y) << 16);
    u.z = (unsigned)__half_as_ushort(h2.x) | ((unsigned)__half_as_ushort(h2.y) << 16);
    u.w = (unsigned)__half_as_ushort(h3.x) | ((unsigned)__half_as_ushort(h3.y) << 16);
    *(uint4*)(xh + (size_t)node * CH + sub * 8) = u;
}

// ---------------- binA: per-tile bucket histogram (no global atomics) -------
__global__ __launch_bounds__(256) void binA_kernel(const int* __restrict__ dst,
                                                   int* __restrict__ tileHist, int E)
{
    __shared__ int h[256];
    int tid = threadIdx.x;
    int t = blockIdx.x;
    h[tid] = 0;
    __syncthreads();
    int e0 = t * TILE + tid * EPT;
    if (e0 + EPT <= E) {
        const int4* dp = (const int4*)(dst + e0);
        int4 a = dp[0], b = dp[1];
        atomicAdd(&h[a.x >> BSH], 1); atomicAdd(&h[a.y >> BSH], 1);
        atomicAdd(&h[a.z >> BSH], 1); atomicAdd(&h[a.w >> BSH], 1);
        atomicAdd(&h[b.x >> BSH], 1); atomicAdd(&h[b.y >> BSH], 1);
        atomicAdd(&h[b.z >> BSH], 1); atomicAdd(&h[b.w >> BSH], 1);
    } else {
        for (int k = e0; k < E && k < e0 + EPT; ++k) atomicAdd(&h[dst[k] >> BSH], 1);
    }
    __syncthreads();
    tileHist[t * 256 + tid] = h[tid];
}

// ---------------- binB: per-bucket exclusive scan over tiles (in place) -----
__global__ __launch_bounds__(256) void binB_kernel(int* __restrict__ tileHist,
                                                   int* __restrict__ totals, int NT)
{
    __shared__ int sm[256];
    int b = blockIdx.x, tid = threadIdx.x;
    int C = (NT + 255) / 256;
    int vals[8];
    int s = 0;
    for (int k = 0; k < C; ++k) {
        int t = tid * C + k;
        vals[k] = (t < NT) ? tileHist[t * 256 + b] : 0;
        s += vals[k];
    }
    sm[tid] = s;
    __syncthreads();
    for (int d = 1; d < 256; d <<= 1) {
        int v = (tid >= d) ? sm[tid - d] : 0;
        __syncthreads();
        sm[tid] += v;
        __syncthreads();
    }
    int off = (tid > 0) ? sm[tid - 1] : 0;
    for (int k = 0; k < C; ++k) {
        int t = tid * C + k;
        if (t < NT) { tileHist[t * 256 + b] = off; off += vals[k]; }
    }
    if (tid == 255) totals[b] = sm[255];
}

// ---------------- binB2: exclusive scan of bucket totals (1 block) ----------
__global__ __launch_bounds__(256) void binB2_kernel(const int* __restrict__ totals,
                                                    int* __restrict__ bucketBase, int NB)
{
    __shared__ int sm[256];
    int tid = threadIdx.x;
    sm[tid] = (tid < NB) ? totals[tid] : 0;
    __syncthreads();
    for (int d = 1; d < 256; d <<= 1) {
        int v = (tid >= d) ? sm[tid - d] : 0;
        __syncthreads();
        sm[tid] += v;
        __syncthreads();
    }
    if (tid < NB) bucketBase[tid] = (tid > 0) ? sm[tid - 1] : 0;
    if (tid == 0) bucketBase[NB] = sm[NB - 1];
}

// ---------------- binC: scatter packed (src<<9|dl) to exact positions -------
__global__ __launch_bounds__(256) void binC_kernel(const int* __restrict__ src,
                                                   const int* __restrict__ dst,
                                                   const int* __restrict__ tileBase,
                                                   const int* __restrict__ bucketBase,
                                                   int* __restrict__ sorted, int E, int NB)
{
    __shared__ int cur[256];
    int tid = threadIdx.x;
    int t = blockIdx.x;
    cur[tid] = (tid < NB) ? bucketBase[tid] + tileBase[t * 256 + tid] : 0;
    __syncthreads();
    int e0 = t * TILE + tid * EPT;
    int s[EPT], d[EPT];
    int nk = 0;
    if (e0 + EPT <= E) {
        const int4* sp = (const int4*)(src + e0);
        const int4* dp = (const int4*)(dst + e0);
        int4 a = sp[0], b = sp[1], c = dp[0], f = dp[1];
        s[0]=a.x; s[1]=a.y; s[2]=a.z; s[3]=a.w; s[4]=b.x; s[5]=b.y; s[6]=b.z; s[7]=b.w;
        d[0]=c.x; d[1]=c.y; d[2]=c.z; d[3]=c.w; d[4]=f.x; d[5]=f.y; d[6]=f.z; d[7]=f.w;
        nk = EPT;
    } else {
        for (int k = 0; e0 + k < E && k < EPT; ++k) { s[k] = src[e0+k]; d[k] = dst[e0+k]; nk++; }
    }
    for (int k = 0; k < nk; ++k) {
        int p = d[k] >> BSH;
        int pos = atomicAdd(&cur[p], 1);       // LDS atomic; global position is exact
        sorted[pos] = (s[k] << BSH) | (d[k] & (BKT - 1));
    }
}

// ---------------- binD: bucket-local fill of bucket[N][CAP] + cnt -----------
// Block per radix bucket: its 80 KB slice stays L2-hot; LDS cursors = indeg.
__global__ __launch_bounds__(256) void binD_kernel(const int* __restrict__ sorted,
                                                   const int* __restrict__ bucketBase,
                                                   int* __restrict__ bucket,
                                                   int* __restrict__ cnt,
                                                   int* __restrict__ spill,
                                                   int* __restrict__ nspill, int N)
{
    __shared__ int lc[BKT];
    int b = blockIdx.x, tid = threadIdx.x;
    lc[tid] = 0; lc[tid + 256] = 0;
    __syncthreads();
    int beg = bucketBase[b], end = bucketBase[b + 1];
    int nbase = b << BSH;
    for (int i = beg + tid; i < end; i += 256) {
        int v = sorted[i];
        int sv = v >> BSH;
        int dl = v & (BKT - 1);
        int pos = atomicAdd(&lc[dl], 1);
        if (pos < CAP) {
            bucket[(size_t)(nbase + dl) * CAP + pos] = sv;
        } else {                                  // statistically never
            int sp = atomicAdd(nspill, 1);
            if (sp < SPILLMAX) { spill[2*sp] = nbase + dl; spill[2*sp+1] = sv; }
        }
    }
    __syncthreads();
    int n0 = nbase + tid;
    if (n0 < N) cnt[n0] = lc[tid];
    int n1 = nbase + 256 + tid;
    if (n1 < N) cnt[n1] = lc[256 + tid];
}

// ---------------- aggregate: half-wave (32 lanes) per node, half2 per lane --
__global__ __launch_bounds__(256) void agg_kernel(const __half* __restrict__ xh,
                                                  const int* __restrict__ bucket,
                                                  const int* __restrict__ cnt,
                                                  const int* __restrict__ spill,
                                                  const int* __restrict__ nspill,
                                                  __half* __restrict__ aggh, int N)
{
    int node = (blockIdx.x * blockDim.x + threadIdx.x) >> 5;
    int sl = threadIdx.x & 31;
    if (node >= N) return;
    int c = cnt[node];
    int m = (c < CAP) ? c : CAP;
    const int* bp = bucket + (size_t)node * CAP;
    float ax0 = 0, ay0 = 0, ax1 = 0, ay1 = 0, ax2 = 0, ay2 = 0, ax3 = 0, ay3 = 0;
    int j = 0;
    for (; j + 4 <= m; j += 4) {
        int s0 = bp[j + 0], s1 = bp[j + 1], s2 = bp[j + 2], s3 = bp[j + 3];
        float2 f0 = __half22float2(*(const __half2*)(xh + (size_t)s0 * CH + sl * 2));
        float2 f1 = __half22float2(*(const __half2*)(xh + (size_t)s1 * CH + sl * 2));
        float2 f2 = __half22float2(*(const __half2*)(xh + (size_t)s2 * CH + sl * 2));
        float2 f3 = __half22float2(*(const __half2*)(xh + (size_t)s3 * CH + sl * 2));
        ax0 += f0.x; ay0 += f0.y;
        ax1 += f1.x; ay1 += f1.y;
        ax2 += f2.x; ay2 += f2.y;
        ax3 += f3.x; ay3 += f3.y;
    }
    for (; j < m; ++j) {
        float2 f = __half22float2(*(const __half2*)(xh + (size_t)bp[j] * CH + sl * 2));
        ax0 += f.x; ay0 += f.y;
    }
    if (c > CAP) {   // cold spill sweep
        int ns = *nspill;
        if (ns > SPILLMAX) ns = SPILLMAX;
        for (int i = 0; i < ns; ++i) {
            if (spill[2 * i] == node) {
                float2 f = __half22float2(*(const __half2*)(xh + (size_t)spill[2 * i + 1] * CH + sl * 2));
                ax0 += f.x; ay0 += f.y;
            }
        }
    }
    float nd = (c > 0) ? rsqrtf((float)c) : 0.0f;
    float rx = ((ax0 + ax1) + (ax2 + ax3)) * nd;
    float ry = ((ay0 + ay1) + (ay2 + ay3)) * nd;
    *(__half2*)(aggh + (size_t)node * CH + sl * 2) = __floats2half2_rn(rx, ry);
}

// ---------------- out = aggh @ W + bias  (row per thread, W scalarized) -----
__global__ __launch_bounds__(256) void gemm_out_kernel(const __half* __restrict__ aggh,
                                                       const float* __restrict__ W,
                                                       const float* __restrict__ bias,
                                                       float* __restrict__ out, int N)
{
    int row = blockIdx.x * blockDim.x + threadIdx.x;
    if (row >= N) return;
    float xr[CH];
    const __half2* xp = (const __half2*)(aggh + (size_t)row * CH);
    #pragma unroll
    for (int j = 0; j < CH / 2; ++j) {
        float2 f = __half22float2(xp[j]);
        xr[2 * j + 0] = f.x;
        xr[2 * j + 1] = f.y;
    }
    float* op = out + (size_t)row * CH;
    for (int c0 = 0; c0 < CH; c0 += 16) {
        float acc[16];
        #pragma unroll
        for (int q = 0; q < 16; ++q) acc[q] = 0.0f;
        #pragma unroll 8
        for (int k = 0; k < CH; ++k) {
            const float xk = xr[k];
            #pragma unroll
            for (int q = 0; q < 4; ++q) {
                float4 w = *(const float4*)(W + k * CH + c0 + q * 4);  // wave-uniform -> s_load
                acc[q * 4 + 0] += xk * w.x;
                acc[q * 4 + 1] += xk * w.y;
                acc[q * 4 + 2] += xk * w.z;
                acc[q * 4 + 3] += xk * w.w;
            }
        }
        #pragma unroll
        for (int q = 0; q < 4; ++q) {
            float4 b = *(const float4*)(bias + c0 + q * 4);
            float4 o;
            o.x = acc[q * 4 + 0] + b.x;
            o.y = acc[q * 4 + 1] + b.y;
            o.z = acc[q * 4 + 2] + b.z;
            o.w = acc[q * 4 + 3] + b.w;
            *(float4*)(op + c0 + q * 4) = o;
        }
    }
}

extern "C" void kernel_launch(void* const* d_in, const int* in_sizes, int n_in,
                              void* d_out, int out_size, void* d_ws, size_t ws_size,
                              hipStream_t stream)
{
    const float* x    = (const float*)d_in[0];
    const int*   edge = (const int*)d_in[1];
    const float* W    = (const float*)d_in[2];
    const float* bias = (const float*)d_in[3];
    float* out = (float*)d_out;

    int N = in_sizes[0] / CH;   // 100000
    int E = in_sizes[1] / 2;    // 1280000
    const int* src = edge;
    const int* dst = edge + E;
    int R  = (N + RANGE - 1) / RANGE;        // 8
    int NT = (E + TILE - 1) / TILE;          // 625
    int NB = (N + BKT - 1) >> BSH;           // 196

    // workspace (ints 4B):
    // [nspill 64][spill 2*SPILLMAX][outdeg N][cnt N][bucket N*CAP]
    // [partial SLICES*R*RANGE ~25.6MB  — REUSED after reduce as:
    //     tileHist NT*256 | totals 256 | bucketBase 257+pad | sorted E ]
    // [align][xh N*CH halves][align][aggh N*CH halves]         (~68 MB total)
    int* nspill  = (int*)d_ws;
    int* spill   = nspill + 64;
    int* outdeg  = spill + 2 * SPILLMAX;
    int* cnt     = outdeg + N;
    int* bucket  = cnt + N;
    int* partial = bucket + (size_t)N * CAP;
    // overlay inside partial (dead after odeg_reduce):
    int* tileHist   = partial;
    int* totals     = tileHist + NT * 256;
    int* bucketBase = totals + 256;
    int* sorted     = bucketBase + 320;
    size_t xoff = (((char*)(partial + (size_t)SLICES * R * RANGE) - (char*)d_ws) + 255) & ~(size_t)255;
    __half* xh = (__half*)((char*)d_ws + xoff);
    size_t aoff = ((xoff + (size_t)N * CH * sizeof(__half)) + 255) & ~(size_t)255;
    __half* aggh = (__half*)((char*)d_ws + aoff);

    hipMemsetAsync(nspill, 0, 64 * sizeof(int), stream);

    // chain 1: outdeg -> prescale (uses partial, freed after reduce)
    hist_kernel<<<R * SLICES, 256, 0, stream>>>(src, partial, E, N, R);
    odeg_reduce_kernel<<<(N + 255) / 256, 256, 0, stream>>>(partial, outdeg, N, R);
    prescale_kernel<<<(N * (CH / 8) + 255) / 256, 256, 0, stream>>>(x, outdeg, xh, N);
    // chain 2: no-atomic radix partition -> per-node buckets
    binA_kernel<<<NT, 256, 0, stream>>>(dst, tileHist, E);
    binB_kernel<<<NB, 256, 0, stream>>>(tileHist, totals, NT);
    binB2_kernel<<<1, 256, 0, stream>>>(totals, bucketBase, NB);
    binC_kernel<<<NT, 256, 0, stream>>>(src, dst, tileHist, bucketBase, sorted, E, NB);
    binD_kernel<<<NB, 256, 0, stream>>>(sorted, bucketBase, bucket, cnt, spill, nspill, N);
    // aggregate + output GEMM
    agg_kernel<<<((size_t)N * 32 + 255) / 256, 256, 0, stream>>>(xh, bucket, cnt, spill,
                                                                 nspill, aggh, N);
    gemm_out_kernel<<<(N + 255) / 256, 256, 0, stream>>>(aggh, W, bias, out, N);
}

// Round 13
// 128.136 us; speedup vs baseline: 6.7691x; 1.0992x over previous
//
#include <hip/hip_runtime.h>
#include <hip/hip_fp16.h>

#define CH 64
#define CAP 40        // per-node bucket capacity; indeg ~ Poisson(12.8), P(>=40) ~ 7e-10
#define SPILLMAX 4096
#define RANGE 12500   // outdeg-histogram bins per block (50 KB LDS)
#define SLICES 64     // 8 ranges x 64 slices = 512 blocks
#define TILE 2048     // edges per binA/binC block
#define EPT 8         // edges per thread (256 * 8 = 2048)
#define BSH 9         // 512 dsts per radix bucket
#define BKT 512

// ---------------- outdeg: privatized LDS histograms (zero global atomics) ---
// partial is u16: per-slice per-bin count <= E/SLICES = 20000 < 65535 always.
__global__ __launch_bounds__(256) void hist_kernel(const int* __restrict__ src,
                                                   unsigned short* __restrict__ partial,
                                                   int E, int N, int R)
{
    __shared__ int h[RANGE];
    int r  = blockIdx.x % R;
    int sl = blockIdx.x / R;
    int lo = r * RANGE;
    int hi = min(lo + RANGE, N);
    int span = hi - lo;
    for (int i = threadIdx.x; i < span; i += 256) h[i] = 0;
    __syncthreads();
    int per = (E + SLICES - 1) / SLICES;
    int sb = sl * per, se = min(sb + per, E);
    for (int e = sb + threadIdx.x * 4; e < se; e += 256 * 4) {
        if (e + 4 <= se) {
            int4 v = *(const int4*)(src + e);
            if (v.x >= lo && v.x < hi) atomicAdd(&h[v.x - lo], 1);
            if (v.y >= lo && v.y < hi) atomicAdd(&h[v.y - lo], 1);
            if (v.z >= lo && v.z < hi) atomicAdd(&h[v.z - lo], 1);
            if (v.w >= lo && v.w < hi) atomicAdd(&h[v.w - lo], 1);
        } else {
            for (int k = e; k < se; ++k) {
                int sv = src[k];
                if (sv >= lo && sv < hi) atomicAdd(&h[sv - lo], 1);
            }
        }
    }
    __syncthreads();
    unsigned short* pp = partial + (size_t)blockIdx.x * RANGE;
    for (int i = threadIdx.x; i < span; i += 256) pp[i] = (unsigned short)h[i];
}

__global__ __launch_bounds__(256) void odeg_reduce_kernel(const unsigned short* __restrict__ partial,
                                                          int* __restrict__ outdeg,
                                                          int N, int R)
{
    int n = blockIdx.x * 256 + threadIdx.x;
    if (n >= N) return;
    int r = n / RANGE, off = n - r * RANGE;
    int s = 0;
    #pragma unroll 8
    for (int sl = 0; sl < SLICES; ++sl)
        s += partial[(size_t)(sl * R + r) * RANGE + off];
    outdeg[n] = s;
}

// ---------------- prescale: xh[n] = rsqrt(outdeg[n]) * x[n]  (fp16) ---------
__global__ __launch_bounds__(256) void prescale_kernel(const float* __restrict__ x,
                                                       const int* __restrict__ outdeg,
                                                       __half* __restrict__ xh, int N)
{
    int g = blockIdx.x * blockDim.x + threadIdx.x;
    int total = N * (CH / 8);
    if (g >= total) return;
    int node = g >> 3, sub = g & 7;
    int od = outdeg[node];
    float ns = (od > 0) ? rsqrtf((float)od) : 0.0f;
    const float4* xp = (const float4*)(x + (size_t)node * CH + sub * 8);
    float4 a = xp[0], b = xp[1];
    __half2 h0 = __floats2half2_rn(a.x * ns, a.y * ns);
    __half2 h1 = __floats2half2_rn(a.z * ns, a.w * ns);
    __half2 h2 = __floats2half2_rn(b.x * ns, b.y * ns);
    __half2 h3 = __floats2half2_rn(b.z * ns, b.w * ns);
    uint4 u;
    u.x = (unsigned)__half_as_ushort(h0.x) | ((unsigned)__half_as_ushort(h0.y) << 16);
    u.y = (unsigned)__half_as_ushort(h1.x) | ((unsigned)__half_as_ushort(h1.y) << 16);
    u.z = (unsigned)__half_as_ushort(h2.x) | ((unsigned)__half_as_ushort(h2.y) << 16);
    u.w = (unsigned)__half_as_ushort(h3.x) | ((unsigned)__half_as_ushort(h3.y) << 16);
    *(uint4*)(xh + (size_t)node * CH + sub * 8) = u;
}

// ---------------- binA: per-tile bucket histogram (no global atomics) -------
__global__ __launch_bounds__(256) void binA_kernel(const int* __restrict__ dst,
                                                   int* __restrict__ tileHist, int E)
{
    __shared__ int h[256];
    int tid = threadIdx.x;
    int t = blockIdx.x;
    h[tid] = 0;
    __syncthreads();
    int e0 = t * TILE + tid * EPT;
    if (e0 + EPT <= E) {
        const int4* dp = (const int4*)(dst + e0);
        int4 a = dp[0], b = dp[1];
        atomicAdd(&h[a.x >> BSH], 1); atomicAdd(&h[a.y >> BSH], 1);
        atomicAdd(&h[a.z >> BSH], 1); atomicAdd(&h[a.w >> BSH], 1);
        atomicAdd(&h[b.x >> BSH], 1); atomicAdd(&h[b.y >> BSH], 1);
        atomicAdd(&h[b.z >> BSH], 1); atomicAdd(&h[b.w >> BSH], 1);
    } else {
        for (int k = e0; k < E && k < e0 + EPT; ++k) atomicAdd(&h[dst[k] >> BSH], 1);
    }
    __syncthreads();
    tileHist[t * 256 + tid] = h[tid];
}

// ---------------- binB: per-bucket exclusive scan over tiles (in place) -----
__global__ __launch_bounds__(256) void binB_kernel(int* __restrict__ tileHist,
                                                   int* __restrict__ totals, int NT)
{
    __shared__ int sm[256];
    int b = blockIdx.x, tid = threadIdx.x;
    int C = (NT + 255) / 256;
    int vals[8];
    int s = 0;
    for (int k = 0; k < C; ++k) {
        int t = tid * C + k;
        vals[k] = (t < NT) ? tileHist[t * 256 + b] : 0;
        s += vals[k];
    }
    sm[tid] = s;
    __syncthreads();
    for (int d = 1; d < 256; d <<= 1) {
        int v = (tid >= d) ? sm[tid - d] : 0;
        __syncthreads();
        sm[tid] += v;
        __syncthreads();
    }
    int off = (tid > 0) ? sm[tid - 1] : 0;
    for (int k = 0; k < C; ++k) {
        int t = tid * C + k;
        if (t < NT) { tileHist[t * 256 + b] = off; off += vals[k]; }
    }
    if (tid == 255) totals[b] = sm[255];
}

// ---------------- binB2: exclusive scan of bucket totals (1 block) ----------
__global__ __launch_bounds__(256) void binB2_kernel(const int* __restrict__ totals,
                                                    int* __restrict__ bucketBase, int NB)
{
    __shared__ int sm[256];
    int tid = threadIdx.x;
    sm[tid] = (tid < NB) ? totals[tid] : 0;
    __syncthreads();
    for (int d = 1; d < 256; d <<= 1) {
        int v = (tid >= d) ? sm[tid - d] : 0;
        __syncthreads();
        sm[tid] += v;
        __syncthreads();
    }
    if (tid < NB) bucketBase[tid] = (tid > 0) ? sm[tid - 1] : 0;
    if (tid == 0) bucketBase[NB] = sm[NB - 1];
}

// ---------------- binC: scatter packed (src<<9|dl) to exact positions -------
__global__ __launch_bounds__(256) void binC_kernel(const int* __restrict__ src,
                                                   const int* __restrict__ dst,
                                                   const int* __restrict__ tileBase,
                                                   const int* __restrict__ bucketBase,
                                                   int* __restrict__ sorted, int E, int NB)
{
    __shared__ int cur[256];
    int tid = threadIdx.x;
    int t = blockIdx.x;
    cur[tid] = (tid < NB) ? bucketBase[tid] + tileBase[t * 256 + tid] : 0;
    __syncthreads();
    int e0 = t * TILE + tid * EPT;
    int s[EPT], d[EPT];
    int nk = 0;
    if (e0 + EPT <= E) {
        const int4* sp = (const int4*)(src + e0);
        const int4* dp = (const int4*)(dst + e0);
        int4 a = sp[0], b = sp[1], c = dp[0], f = dp[1];
        s[0]=a.x; s[1]=a.y; s[2]=a.z; s[3]=a.w; s[4]=b.x; s[5]=b.y; s[6]=b.z; s[7]=b.w;
        d[0]=c.x; d[1]=c.y; d[2]=c.z; d[3]=c.w; d[4]=f.x; d[5]=f.y; d[6]=f.z; d[7]=f.w;
        nk = EPT;
    } else {
        for (int k = 0; e0 + k < E && k < EPT; ++k) { s[k] = src[e0+k]; d[k] = dst[e0+k]; nk++; }
    }
    for (int k = 0; k < nk; ++k) {
        int p = d[k] >> BSH;
        int pos = atomicAdd(&cur[p], 1);       // LDS atomic; global position is exact
        sorted[pos] = (s[k] << BSH) | (d[k] & (BKT - 1));
    }
}

// ---------------- binD: bucket-local fill of bucket[N][CAP] + cnt -----------
__global__ __launch_bounds__(256) void binD_kernel(const int* __restrict__ sorted,
                                                   const int* __restrict__ bucketBase,
                                                   int* __restrict__ bucket,
                                                   int* __restrict__ cnt,
                                                   int* __restrict__ spill,
                                                   int* __restrict__ nspill, int N)
{
    __shared__ int lc[BKT];
    int b = blockIdx.x, tid = threadIdx.x;
    lc[tid] = 0; lc[tid + 256] = 0;
    __syncthreads();
    int beg = bucketBase[b], end = bucketBase[b + 1];
    int nbase = b << BSH;
    for (int i = beg + tid; i < end; i += 256) {
        int v = sorted[i];
        int sv = v >> BSH;
        int dl = v & (BKT - 1);
        int pos = atomicAdd(&lc[dl], 1);
        if (pos < CAP) {
            bucket[(size_t)(nbase + dl) * CAP + pos] = sv;
        } else {                                  // statistically never
            int sp = atomicAdd(nspill, 1);
            if (sp < SPILLMAX) { spill[2*sp] = nbase + dl; spill[2*sp+1] = sv; }
        }
    }
    __syncthreads();
    int n0 = nbase + tid;
    if (n0 < N) cnt[n0] = lc[tid];
    int n1 = nbase + 256 + tid;
    if (n1 < N) cnt[n1] = lc[256 + tid];
}

// ---------------- aggregate: half-wave (32 lanes) per node, half2 per lane --
__global__ __launch_bounds__(256) void agg_kernel(const __half* __restrict__ xh,
                                                  const int* __restrict__ bucket,
                                                  const int* __restrict__ cnt,
                                                  const int* __restrict__ spill,
                                                  const int* __restrict__ nspill,
                                                  __half* __restrict__ aggh, int N)
{
    int node = (blockIdx.x * blockDim.x + threadIdx.x) >> 5;
    int sl = threadIdx.x & 31;
    if (node >= N) return;
    int c = cnt[node];
    int m = (c < CAP) ? c : CAP;
    const int* bp = bucket + (size_t)node * CAP;
    float ax0 = 0, ay0 = 0, ax1 = 0, ay1 = 0, ax2 = 0, ay2 = 0, ax3 = 0, ay3 = 0;
    int j = 0;
    for (; j + 4 <= m; j += 4) {
        int s0 = bp[j + 0], s1 = bp[j + 1], s2 = bp[j + 2], s3 = bp[j + 3];
        float2 f0 = __half22float2(*(const __half2*)(xh + (size_t)s0 * CH + sl * 2));
        float2 f1 = __half22float2(*(const __half2*)(xh + (size_t)s1 * CH + sl * 2));
        float2 f2 = __half22float2(*(const __half2*)(xh + (size_t)s2 * CH + sl * 2));
        float2 f3 = __half22float2(*(const __half2*)(xh + (size_t)s3 * CH + sl * 2));
        ax0 += f0.x; ay0 += f0.y;
        ax1 += f1.x; ay1 += f1.y;
        ax2 += f2.x; ay2 += f2.y;
        ax3 += f3.x; ay3 += f3.y;
    }
    for (; j < m; ++j) {
        float2 f = __half22float2(*(const __half2*)(xh + (size_t)bp[j] * CH + sl * 2));
        ax0 += f.x; ay0 += f.y;
    }
    if (c > CAP) {   // cold spill sweep
        int ns = *nspill;
        if (ns > SPILLMAX) ns = SPILLMAX;
        for (int i = 0; i < ns; ++i) {
            if (spill[2 * i] == node) {
                float2 f = __half22float2(*(const __half2*)(xh + (size_t)spill[2 * i + 1] * CH + sl * 2));
                ax0 += f.x; ay0 += f.y;
            }
        }
    }
    float nd = (c > 0) ? rsqrtf((float)c) : 0.0f;
    float rx = ((ax0 + ax1) + (ax2 + ax3)) * nd;
    float ry = ((ay0 + ay1) + (ay2 + ay3)) * nd;
    *(__half2*)(aggh + (size_t)node * CH + sl * 2) = __floats2half2_rn(rx, ry);
}

// ---------------- out = aggh @ W + bias -------------------------------------
// Wave = 64 rows x one 32-ch half (half is wave-uniform -> W/bias stay s_load).
// aggh row consumed in uint4 chunks (no scalar reloads); 128B contiguous store.
__global__ __launch_bounds__(256) void gemm_out_kernel(const __half* __restrict__ aggh,
                                                       const float* __restrict__ W,
                                                       const float* __restrict__ bias,
                                                       float* __restrict__ out, int N)
{
    int g = blockIdx.x * 256 + threadIdx.x;
    int waveId = __builtin_amdgcn_readfirstlane(g >> 6);   // wave-uniform by construction
    int lane = threadIdx.x & 63;
    int half = waveId & 1;
    int row = ((waveId >> 1) << 6) + lane;
    if (row >= N) return;
    const int cbase = half * 32;                            // scalar
    float acc[32];
    #pragma unroll
    for (int i = 0; i < 32; ++i) acc[i] = 0.0f;
    const __half* xp = aggh + (size_t)row * CH;
    for (int k0 = 0; k0 < CH; k0 += 8) {
        uint4 u = *(const uint4*)(xp + k0);                 // 8 halves, one 16B load
        const __half2* hp = (const __half2*)&u;
        float xk[8];
        #pragma unroll
        for (int j = 0; j < 4; ++j) {
            float2 f = __half22float2(hp[j]);
            xk[2 * j] = f.x; xk[2 * j + 1] = f.y;
        }
        #pragma unroll
        for (int kk = 0; kk < 8; ++kk) {
            const float* wrow = W + (k0 + kk) * CH + cbase; // wave-uniform -> s_load
            #pragma unroll
            for (int q = 0; q < 8; ++q) {
                float4 w = *(const float4*)(wrow + q * 4);
                acc[q * 4 + 0] += xk[kk] * w.x;
                acc[q * 4 + 1] += xk[kk] * w.y;
                acc[q * 4 + 2] += xk[kk] * w.z;
                acc[q * 4 + 3] += xk[kk] * w.w;
            }
        }
    }
    float* op = out + (size_t)row * CH + cbase;
    #pragma unroll
    for (int q = 0; q < 8; ++q) {
        float4 b = *(const float4*)(bias + cbase + q * 4);  // wave-uniform
        float4 o;
        o.x = acc[q * 4 + 0] + b.x;
        o.y = acc[q * 4 + 1] + b.y;
        o.z = acc[q * 4 + 2] + b.z;
        o.w = acc[q * 4 + 3] + b.w;
        *(float4*)(op + q * 4) = o;                          // 128B contiguous per lane
    }
}

extern "C" void kernel_launch(void* const* d_in, const int* in_sizes, int n_in,
                              void* d_out, int out_size, void* d_ws, size_t ws_size,
                              hipStream_t stream)
{
    const float* x    = (const float*)d_in[0];
    const int*   edge = (const int*)d_in[1];
    const float* W    = (const float*)d_in[2];
    const float* bias = (const float*)d_in[3];
    float* out = (float*)d_out;

    int N = in_sizes[0] / CH;   // 100000
    int E = in_sizes[1] / 2;    // 1280000
    const int* src = edge;
    const int* dst = edge + E;
    int R  = (N + RANGE - 1) / RANGE;        // 8
    int NT = (E + TILE - 1) / TILE;          // 625
    int NB = (N + BKT - 1) >> BSH;           // 196

    // workspace (ints 4B unless noted):
    // [nspill 64][spill 2*SPILLMAX][outdeg N][cnt N][bucket N*CAP]
    // [partial u16 SLICES*R*RANGE ~12.8MB — REUSED after reduce as:
    //     tileHist NT*256 | totals 256 | bucketBase 320 | sorted E ]  (~5.8MB used)
    // [align][xh N*CH halves][align][aggh N*CH halves]
    int* nspill  = (int*)d_ws;
    int* spill   = nspill + 64;
    int* outdeg  = spill + 2 * SPILLMAX;
    int* cnt     = outdeg + N;
    int* bucket  = cnt + N;
    unsigned short* partial = (unsigned short*)(bucket + (size_t)N * CAP);
    // overlay inside partial (dead after odeg_reduce):
    int* tileHist   = (int*)partial;
    int* totals     = tileHist + NT * 256;
    int* bucketBase = totals + 256;
    int* sorted     = bucketBase + 320;
    size_t psz = (size_t)SLICES * R * RANGE * sizeof(unsigned short);
    size_t osz = (size_t)(NT * 256 + 256 + 320 + E) * sizeof(int);
    size_t xoff = ((((char*)partial - (char*)d_ws) + (psz > osz ? psz : osz)) + 255) & ~(size_t)255;
    __half* xh = (__half*)((char*)d_ws + xoff);
    size_t aoff = ((xoff + (size_t)N * CH * sizeof(__half)) + 255) & ~(size_t)255;
    __half* aggh = (__half*)((char*)d_ws + aoff);

    hipMemsetAsync(nspill, 0, 64 * sizeof(int), stream);

    // chain 1: outdeg -> prescale (uses partial, freed after reduce)
    hist_kernel<<<R * SLICES, 256, 0, stream>>>(src, partial, E, N, R);
    odeg_reduce_kernel<<<(N + 255) / 256, 256, 0, stream>>>(partial, outdeg, N, R);
    prescale_kernel<<<(N * (CH / 8) + 255) / 256, 256, 0, stream>>>(x, outdeg, xh, N);
    // chain 2: no-atomic radix partition -> per-node buckets
    binA_kernel<<<NT, 256, 0, stream>>>(dst, tileHist, E);
    binB_kernel<<<NB, 256, 0, stream>>>(tileHist, totals, NT);
    binB2_kernel<<<1, 256, 0, stream>>>(totals, bucketBase, NB);
    binC_kernel<<<NT, 256, 0, stream>>>(src, dst, tileHist, bucketBase, sorted, E, NB);
    binD_kernel<<<NB, 256, 0, stream>>>(sorted, bucketBase, bucket, cnt, spill, nspill, N);
    // aggregate + output GEMM
    agg_kernel<<<((size_t)N * 32 + 255) / 256, 256, 0, stream>>>(xh, bucket, cnt, spill,
                                                                 nspill, aggh, N);
    int nwaves = 2 * ((N + 63) / 64);
    gemm_out_kernel<<<(nwaves + 3) / 4, 256, 0, stream>>>(aggh, W, bias, out, N);
}

// Round 14
// 123.508 us; speedup vs baseline: 7.0227x; 1.0375x over previous
//
#include <hip/hip_runtime.h>
#include <hip/hip_fp16.h>

#define CH 64
#define CAP 40        // per-node bucket capacity; indeg ~ Poisson(12.8), P(>=40) ~ 7e-10
#define SPILLMAX 4096
#define RANGE 12500   // outdeg-histogram bins per block (50 KB LDS)
#define SLICES 64     // 8 ranges x 64 slices = 512 blocks
#define TILE 2048     // edges per binA/binC block
#define EPT 8         // edges per thread (256 * 8 = 2048)
#define BSH 9         // 512 dsts per radix bucket
#define BKT 512

// ---------------- outdeg: privatized LDS histograms (zero global atomics) ---
// partial is u16: per-slice per-bin count <= E/SLICES = 20000 < 65535 always.
__global__ __launch_bounds__(256) void hist_kernel(const int* __restrict__ src,
                                                   unsigned short* __restrict__ partial,
                                                   int E, int N, int R)
{
    __shared__ int h[RANGE];
    int r  = blockIdx.x % R;
    int sl = blockIdx.x / R;
    int lo = r * RANGE;
    int hi = min(lo + RANGE, N);
    int span = hi - lo;
    for (int i = threadIdx.x; i < span; i += 256) h[i] = 0;
    __syncthreads();
    int per = (E + SLICES - 1) / SLICES;
    int sb = sl * per, se = min(sb + per, E);
    for (int e = sb + threadIdx.x * 4; e < se; e += 256 * 4) {
        if (e + 4 <= se) {
            int4 v = *(const int4*)(src + e);
            if (v.x >= lo && v.x < hi) atomicAdd(&h[v.x - lo], 1);
            if (v.y >= lo && v.y < hi) atomicAdd(&h[v.y - lo], 1);
            if (v.z >= lo && v.z < hi) atomicAdd(&h[v.z - lo], 1);
            if (v.w >= lo && v.w < hi) atomicAdd(&h[v.w - lo], 1);
        } else {
            for (int k = e; k < se; ++k) {
                int sv = src[k];
                if (sv >= lo && sv < hi) atomicAdd(&h[sv - lo], 1);
            }
        }
    }
    __syncthreads();
    unsigned short* pp = partial + (size_t)blockIdx.x * RANGE;
    for (int i = threadIdx.x; i < span; i += 256) pp[i] = (unsigned short)h[i];
}

__global__ __launch_bounds__(256) void odeg_reduce_kernel(const unsigned short* __restrict__ partial,
                                                          int* __restrict__ outdeg,
                                                          int N, int R)
{
    int n = blockIdx.x * 256 + threadIdx.x;
    if (n >= N) return;
    int r = n / RANGE, off = n - r * RANGE;
    int s = 0;
    #pragma unroll 8
    for (int sl = 0; sl < SLICES; ++sl)
        s += partial[(size_t)(sl * R + r) * RANGE + off];
    outdeg[n] = s;
}

// ---------------- prescale: xh[n] = rsqrt(outdeg[n]) * x[n]  (fp16) ---------
__global__ __launch_bounds__(256) void prescale_kernel(const float* __restrict__ x,
                                                       const int* __restrict__ outdeg,
                                                       __half* __restrict__ xh, int N)
{
    int g = blockIdx.x * blockDim.x + threadIdx.x;
    int total = N * (CH / 8);
    if (g >= total) return;
    int node = g >> 3, sub = g & 7;
    int od = outdeg[node];
    float ns = (od > 0) ? rsqrtf((float)od) : 0.0f;
    const float4* xp = (const float4*)(x + (size_t)node * CH + sub * 8);
    float4 a = xp[0], b = xp[1];
    __half2 h0 = __floats2half2_rn(a.x * ns, a.y * ns);
    __half2 h1 = __floats2half2_rn(a.z * ns, a.w * ns);
    __half2 h2 = __floats2half2_rn(b.x * ns, b.y * ns);
    __half2 h3 = __floats2half2_rn(b.z * ns, b.w * ns);
    uint4 u;
    u.x = (unsigned)__half_as_ushort(h0.x) | ((unsigned)__half_as_ushort(h0.y) << 16);
    u.y = (unsigned)__half_as_ushort(h1.x) | ((unsigned)__half_as_ushort(h1.y) << 16);
    u.z = (unsigned)__half_as_ushort(h2.x) | ((unsigned)__half_as_ushort(h2.y) << 16);
    u.w = (unsigned)__half_as_ushort(h3.x) | ((unsigned)__half_as_ushort(h3.y) << 16);
    *(uint4*)(xh + (size_t)node * CH + sub * 8) = u;
}

// ---------------- binA: per-tile bucket histogram (no global atomics) -------
// Also zeroes nspill (block 0) -- replaces the 41us hipMemsetAsync fill.
__global__ __launch_bounds__(256) void binA_kernel(const int* __restrict__ dst,
                                                   int* __restrict__ tileHist,
                                                   int* __restrict__ nspill, int E)
{
    if (blockIdx.x == 0 && threadIdx.x == 0) nspill[0] = 0;  // consumed 3 kernels later
    __shared__ int h[256];
    int tid = threadIdx.x;
    int t = blockIdx.x;
    h[tid] = 0;
    __syncthreads();
    int e0 = t * TILE + tid * EPT;
    if (e0 + EPT <= E) {
        const int4* dp = (const int4*)(dst + e0);
        int4 a = dp[0], b = dp[1];
        atomicAdd(&h[a.x >> BSH], 1); atomicAdd(&h[a.y >> BSH], 1);
        atomicAdd(&h[a.z >> BSH], 1); atomicAdd(&h[a.w >> BSH], 1);
        atomicAdd(&h[b.x >> BSH], 1); atomicAdd(&h[b.y >> BSH], 1);
        atomicAdd(&h[b.z >> BSH], 1); atomicAdd(&h[b.w >> BSH], 1);
    } else {
        for (int k = e0; k < E && k < e0 + EPT; ++k) atomicAdd(&h[dst[k] >> BSH], 1);
    }
    __syncthreads();
    tileHist[t * 256 + tid] = h[tid];
}

// ---------------- binB: per-bucket exclusive scan over tiles (in place) -----
__global__ __launch_bounds__(256) void binB_kernel(int* __restrict__ tileHist,
                                                   int* __restrict__ totals, int NT)
{
    __shared__ int sm[256];
    int b = blockIdx.x, tid = threadIdx.x;
    int C = (NT + 255) / 256;
    int vals[8];
    int s = 0;
    for (int k = 0; k < C; ++k) {
        int t = tid * C + k;
        vals[k] = (t < NT) ? tileHist[t * 256 + b] : 0;
        s += vals[k];
    }
    sm[tid] = s;
    __syncthreads();
    for (int d = 1; d < 256; d <<= 1) {
        int v = (tid >= d) ? sm[tid - d] : 0;
        __syncthreads();
        sm[tid] += v;
        __syncthreads();
    }
    int off = (tid > 0) ? sm[tid - 1] : 0;
    for (int k = 0; k < C; ++k) {
        int t = tid * C + k;
        if (t < NT) { tileHist[t * 256 + b] = off; off += vals[k]; }
    }
    if (tid == 255) totals[b] = sm[255];
}

// ---------------- binB2: exclusive scan of bucket totals (1 block) ----------
__global__ __launch_bounds__(256) void binB2_kernel(const int* __restrict__ totals,
                                                    int* __restrict__ bucketBase, int NB)
{
    __shared__ int sm[256];
    int tid = threadIdx.x;
    sm[tid] = (tid < NB) ? totals[tid] : 0;
    __syncthreads();
    for (int d = 1; d < 256; d <<= 1) {
        int v = (tid >= d) ? sm[tid - d] : 0;
        __syncthreads();
        sm[tid] += v;
        __syncthreads();
    }
    if (tid < NB) bucketBase[tid] = (tid > 0) ? sm[tid - 1] : 0;
    if (tid == 0) bucketBase[NB] = sm[NB - 1];
}

// ---------------- binC: scatter packed (src<<9|dl) to exact positions -------
__global__ __launch_bounds__(256) void binC_kernel(const int* __restrict__ src,
                                                   const int* __restrict__ dst,
                                                   const int* __restrict__ tileBase,
                                                   const int* __restrict__ bucketBase,
                                                   int* __restrict__ sorted, int E, int NB)
{
    __shared__ int cur[256];
    int tid = threadIdx.x;
    int t = blockIdx.x;
    cur[tid] = (tid < NB) ? bucketBase[tid] + tileBase[t * 256 + tid] : 0;
    __syncthreads();
    int e0 = t * TILE + tid * EPT;
    int s[EPT], d[EPT];
    int nk = 0;
    if (e0 + EPT <= E) {
        const int4* sp = (const int4*)(src + e0);
        const int4* dp = (const int4*)(dst + e0);
        int4 a = sp[0], b = sp[1], c = dp[0], f = dp[1];
        s[0]=a.x; s[1]=a.y; s[2]=a.z; s[3]=a.w; s[4]=b.x; s[5]=b.y; s[6]=b.z; s[7]=b.w;
        d[0]=c.x; d[1]=c.y; d[2]=c.z; d[3]=c.w; d[4]=f.x; d[5]=f.y; d[6]=f.z; d[7]=f.w;
        nk = EPT;
    } else {
        for (int k = 0; e0 + k < E && k < EPT; ++k) { s[k] = src[e0+k]; d[k] = dst[e0+k]; nk++; }
    }
    for (int k = 0; k < nk; ++k) {
        int p = d[k] >> BSH;
        int pos = atomicAdd(&cur[p], 1);       // LDS atomic; global position is exact
        sorted[pos] = (s[k] << BSH) | (d[k] & (BKT - 1));
    }
}

// ---------------- binD: bucket-local fill of bucket[N][CAP] + cnt -----------
__global__ __launch_bounds__(256) void binD_kernel(const int* __restrict__ sorted,
                                                   const int* __restrict__ bucketBase,
                                                   int* __restrict__ bucket,
                                                   int* __restrict__ cnt,
                                                   int* __restrict__ spill,
                                                   int* __restrict__ nspill, int N)
{
    __shared__ int lc[BKT];
    int b = blockIdx.x, tid = threadIdx.x;
    lc[tid] = 0; lc[tid + 256] = 0;
    __syncthreads();
    int beg = bucketBase[b], end = bucketBase[b + 1];
    int nbase = b << BSH;
    for (int i = beg + tid; i < end; i += 256) {
        int v = sorted[i];
        int sv = v >> BSH;
        int dl = v & (BKT - 1);
        int pos = atomicAdd(&lc[dl], 1);
        if (pos < CAP) {
            bucket[(size_t)(nbase + dl) * CAP + pos] = sv;
        } else {                                  // statistically never
            int sp = atomicAdd(nspill, 1);
            if (sp < SPILLMAX) { spill[2*sp] = nbase + dl; spill[2*sp+1] = sv; }
        }
    }
    __syncthreads();
    int n0 = nbase + tid;
    if (n0 < N) cnt[n0] = lc[tid];
    int n1 = nbase + 256 + tid;
    if (n1 < N) cnt[n1] = lc[256 + tid];
}

// ---------------- aggregate: half-wave (32 lanes) per node, half2 per lane --
__global__ __launch_bounds__(256) void agg_kernel(const __half* __restrict__ xh,
                                                  const int* __restrict__ bucket,
                                                  const int* __restrict__ cnt,
                                                  const int* __restrict__ spill,
                                                  const int* __restrict__ nspill,
                                                  __half* __restrict__ aggh, int N)
{
    int node = (blockIdx.x * blockDim.x + threadIdx.x) >> 5;
    int sl = threadIdx.x & 31;
    if (node >= N) return;
    int c = cnt[node];
    int m = (c < CAP) ? c : CAP;
    const int* bp = bucket + (size_t)node * CAP;
    float ax0 = 0, ay0 = 0, ax1 = 0, ay1 = 0, ax2 = 0, ay2 = 0, ax3 = 0, ay3 = 0;
    int j = 0;
    for (; j + 4 <= m; j += 4) {
        int s0 = bp[j + 0], s1 = bp[j + 1], s2 = bp[j + 2], s3 = bp[j + 3];
        float2 f0 = __half22float2(*(const __half2*)(xh + (size_t)s0 * CH + sl * 2));
        float2 f1 = __half22float2(*(const __half2*)(xh + (size_t)s1 * CH + sl * 2));
        float2 f2 = __half22float2(*(const __half2*)(xh + (size_t)s2 * CH + sl * 2));
        float2 f3 = __half22float2(*(const __half2*)(xh + (size_t)s3 * CH + sl * 2));
        ax0 += f0.x; ay0 += f0.y;
        ax1 += f1.x; ay1 += f1.y;
        ax2 += f2.x; ay2 += f2.y;
        ax3 += f3.x; ay3 += f3.y;
    }
    for (; j < m; ++j) {
        float2 f = __half22float2(*(const __half2*)(xh + (size_t)bp[j] * CH + sl * 2));
        ax0 += f.x; ay0 += f.y;
    }
    if (c > CAP) {   // cold spill sweep
        int ns = *nspill;
        if (ns > SPILLMAX) ns = SPILLMAX;
        for (int i = 0; i < ns; ++i) {
            if (spill[2 * i] == node) {
                float2 f = __half22float2(*(const __half2*)(xh + (size_t)spill[2 * i + 1] * CH + sl * 2));
                ax0 += f.x; ay0 += f.y;
            }
        }
    }
    float nd = (c > 0) ? rsqrtf((float)c) : 0.0f;
    float rx = ((ax0 + ax1) + (ax2 + ax3)) * nd;
    float ry = ((ay0 + ay1) + (ay2 + ay3)) * nd;
    *(__half2*)(aggh + (size_t)node * CH + sl * 2) = __floats2half2_rn(rx, ry);
}

// ---------------- out = aggh @ W + bias -------------------------------------
// Wave = 64 rows x one 32-ch half (half is wave-uniform -> W/bias stay s_load).
__global__ __launch_bounds__(256) void gemm_out_kernel(const __half* __restrict__ aggh,
                                                       const float* __restrict__ W,
                                                       const float* __restrict__ bias,
                                                       float* __restrict__ out, int N)
{
    int g = blockIdx.x * 256 + threadIdx.x;
    int waveId = __builtin_amdgcn_readfirstlane(g >> 6);   // wave-uniform by construction
    int lane = threadIdx.x & 63;
    int half = waveId & 1;
    int row = ((waveId >> 1) << 6) + lane;
    if (row >= N) return;
    const int cbase = half * 32;                            // scalar
    float acc[32];
    #pragma unroll
    for (int i = 0; i < 32; ++i) acc[i] = 0.0f;
    const __half* xp = aggh + (size_t)row * CH;
    for (int k0 = 0; k0 < CH; k0 += 8) {
        uint4 u = *(const uint4*)(xp + k0);                 // 8 halves, one 16B load
        const __half2* hp = (const __half2*)&u;
        float xk[8];
        #pragma unroll
        for (int j = 0; j < 4; ++j) {
            float2 f = __half22float2(hp[j]);
            xk[2 * j] = f.x; xk[2 * j + 1] = f.y;
        }
        #pragma unroll
        for (int kk = 0; kk < 8; ++kk) {
            const float* wrow = W + (k0 + kk) * CH + cbase; // wave-uniform -> s_load
            #pragma unroll
            for (int q = 0; q < 8; ++q) {
                float4 w = *(const float4*)(wrow + q * 4);
                acc[q * 4 + 0] += xk[kk] * w.x;
                acc[q * 4 + 1] += xk[kk] * w.y;
                acc[q * 4 + 2] += xk[kk] * w.z;
                acc[q * 4 + 3] += xk[kk] * w.w;
            }
        }
    }
    float* op = out + (size_t)row * CH + cbase;
    #pragma unroll
    for (int q = 0; q < 8; ++q) {
        float4 b = *(const float4*)(bias + cbase + q * 4);  // wave-uniform
        float4 o;
        o.x = acc[q * 4 + 0] + b.x;
        o.y = acc[q * 4 + 1] + b.y;
        o.z = acc[q * 4 + 2] + b.z;
        o.w = acc[q * 4 + 3] + b.w;
        *(float4*)(op + q * 4) = o;                          // 128B contiguous per lane
    }
}

extern "C" void kernel_launch(void* const* d_in, const int* in_sizes, int n_in,
                              void* d_out, int out_size, void* d_ws, size_t ws_size,
                              hipStream_t stream)
{
    const float* x    = (const float*)d_in[0];
    const int*   edge = (const int*)d_in[1];
    const float* W    = (const float*)d_in[2];
    const float* bias = (const float*)d_in[3];
    float* out = (float*)d_out;

    int N = in_sizes[0] / CH;   // 100000
    int E = in_sizes[1] / 2;    // 1280000
    const int* src = edge;
    const int* dst = edge + E;
    int R  = (N + RANGE - 1) / RANGE;        // 8
    int NT = (E + TILE - 1) / TILE;          // 625
    int NB = (N + BKT - 1) >> BSH;           // 196

    // workspace (ints 4B unless noted):
    // [nspill 64][spill 2*SPILLMAX][outdeg N][cnt N][bucket N*CAP]
    // [partial u16 SLICES*R*RANGE ~12.8MB — REUSED after reduce as:
    //     tileHist NT*256 | totals 256 | bucketBase 320 | sorted E ]
    // [align][xh N*CH halves][align][aggh N*CH halves]
    int* nspill  = (int*)d_ws;
    int* spill   = nspill + 64;
    int* outdeg  = spill + 2 * SPILLMAX;
    int* cnt     = outdeg + N;
    int* bucket  = cnt + N;
    unsigned short* partial = (unsigned short*)(bucket + (size_t)N * CAP);
    // overlay inside partial (dead after odeg_reduce):
    int* tileHist   = (int*)partial;
    int* totals     = tileHist + NT * 256;
    int* bucketBase = totals + 256;
    int* sorted     = bucketBase + 320;
    size_t psz = (size_t)SLICES * R * RANGE * sizeof(unsigned short);
    size_t osz = (size_t)(NT * 256 + 256 + 320 + E) * sizeof(int);
    size_t xoff = ((((char*)partial - (char*)d_ws) + (psz > osz ? psz : osz)) + 255) & ~(size_t)255;
    __half* xh = (__half*)((char*)d_ws + xoff);
    size_t aoff = ((xoff + (size_t)N * CH * sizeof(__half)) + 255) & ~(size_t)255;
    __half* aggh = (__half*)((char*)d_ws + aoff);

    // NOTE: no hipMemsetAsync — nspill is zeroed inside binA_kernel (saves the
    // ~41us per-replay fillBufferAligned dispatch observed in round 13).

    // chain 1: outdeg -> prescale (uses partial, freed after reduce)
    hist_kernel<<<R * SLICES, 256, 0, stream>>>(src, partial, E, N, R);
    odeg_reduce_kernel<<<(N + 255) / 256, 256, 0, stream>>>(partial, outdeg, N, R);
    prescale_kernel<<<(N * (CH / 8) + 255) / 256, 256, 0, stream>>>(x, outdeg, xh, N);
    // chain 2: no-atomic radix partition -> per-node buckets
    binA_kernel<<<NT, 256, 0, stream>>>(dst, tileHist, nspill, E);
    binB_kernel<<<NB, 256, 0, stream>>>(tileHist, totals, NT);
    binB2_kernel<<<1, 256, 0, stream>>>(totals, bucketBase, NB);
    binC_kernel<<<NT, 256, 0, stream>>>(src, dst, tileHist, bucketBase, sorted, E, NB);
    binD_kernel<<<NB, 256, 0, stream>>>(sorted, bucketBase, bucket, cnt, spill, nspill, N);
    // aggregate + output GEMM
    agg_kernel<<<((size_t)N * 32 + 255) / 256, 256, 0, stream>>>(xh, bucket, cnt, spill,
                                                                 nspill, aggh, N);
    int nwaves = 2 * ((N + 63) / 64);
    gemm_out_kernel<<<(nwaves + 3) / 4, 256, 0, stream>>>(aggh, W, bias, out, N);
}

// Round 15
// 113.987 us; speedup vs baseline: 7.6093x; 1.0835x over previous
//
#include <hip/hip_runtime.h>
#include <hip/hip_fp16.h>

#define CH 64
#define CAP 40        // per-node bucket capacity; indeg ~ Poisson(12.8), P(>=40) ~ 7e-10
#define SPILLMAX 4096
#define RANGE 12500   // outdeg-histogram bins per block (50 KB LDS)
#define SLICES 64     // 8 ranges x 64 slices = 512 blocks
#define TILE 2048     // edges per binA/binC block
#define EPT 8         // edges per thread (256 * 8 = 2048)
#define BSH 9         // 512 dsts per radix bucket
#define BKT 512

// ---------------- outdeg: privatized LDS histograms (zero global atomics) ---
__global__ __launch_bounds__(256) void hist_kernel(const int* __restrict__ src,
                                                   unsigned short* __restrict__ partial,
                                                   int E, int N, int R)
{
    __shared__ int h[RANGE];
    int r  = blockIdx.x % R;
    int sl = blockIdx.x / R;
    int lo = r * RANGE;
    int hi = min(lo + RANGE, N);
    int span = hi - lo;
    for (int i = threadIdx.x; i < span; i += 256) h[i] = 0;
    __syncthreads();
    int per = (E + SLICES - 1) / SLICES;
    int sb = sl * per, se = min(sb + per, E);
    for (int e = sb + threadIdx.x * 4; e < se; e += 256 * 4) {
        if (e + 4 <= se) {
            int4 v = *(const int4*)(src + e);
            if (v.x >= lo && v.x < hi) atomicAdd(&h[v.x - lo], 1);
            if (v.y >= lo && v.y < hi) atomicAdd(&h[v.y - lo], 1);
            if (v.z >= lo && v.z < hi) atomicAdd(&h[v.z - lo], 1);
            if (v.w >= lo && v.w < hi) atomicAdd(&h[v.w - lo], 1);
        } else {
            for (int k = e; k < se; ++k) {
                int sv = src[k];
                if (sv >= lo && sv < hi) atomicAdd(&h[sv - lo], 1);
            }
        }
    }
    __syncthreads();
    unsigned short* pp = partial + (size_t)blockIdx.x * RANGE;
    for (int i = threadIdx.x; i < span; i += 256) pp[i] = (unsigned short)h[i];
}

// ---------------- fused: outdeg-reduce + prescale (xh = rsqrt(od)*x, fp16) --
// Block handles 256 nodes: phase A thread-per-node partial sum -> LDS rsqrt;
// phase B 8 threads per node, coalesced x read / xh write.
__global__ __launch_bounds__(256) void rpscale_kernel(const unsigned short* __restrict__ partial,
                                                      const float* __restrict__ x,
                                                      __half* __restrict__ xh, int N, int R)
{
    __shared__ float nsl[256];
    int tid = threadIdx.x;
    int n0 = blockIdx.x * 256;
    int n = n0 + tid;
    if (n < N) {
        int r = n / RANGE, off = n - r * RANGE;
        int s = 0;
        #pragma unroll 8
        for (int sl = 0; sl < SLICES; ++sl)
            s += partial[(size_t)(sl * R + r) * RANGE + off];
        nsl[tid] = (s > 0) ? rsqrtf((float)s) : 0.0f;
    } else {
        nsl[tid] = 0.0f;
    }
    __syncthreads();
    int sub = tid & 7;
    int nl0 = tid >> 3;                 // 32 nodes per pass, 8 passes
    for (int p = 0; p < 8; ++p) {
        int nl = p * 32 + nl0;
        int node = n0 + nl;
        if (node >= N) break;
        float ns = nsl[nl];
        const float4* xp = (const float4*)(x + (size_t)node * CH + sub * 8);
        float4 a = xp[0], b = xp[1];
        __half2 h0 = __floats2half2_rn(a.x * ns, a.y * ns);
        __half2 h1 = __floats2half2_rn(a.z * ns, a.w * ns);
        __half2 h2 = __floats2half2_rn(b.x * ns, b.y * ns);
        __half2 h3 = __floats2half2_rn(b.z * ns, b.w * ns);
        uint4 u;
        u.x = (unsigned)__half_as_ushort(h0.x) | ((unsigned)__half_as_ushort(h0.y) << 16);
        u.y = (unsigned)__half_as_ushort(h1.x) | ((unsigned)__half_as_ushort(h1.y) << 16);
        u.z = (unsigned)__half_as_ushort(h2.x) | ((unsigned)__half_as_ushort(h2.y) << 16);
        u.w = (unsigned)__half_as_ushort(h3.x) | ((unsigned)__half_as_ushort(h3.y) << 16);
        *(uint4*)(xh + (size_t)node * CH + sub * 8) = u;
    }
}

// ---------------- binA: per-tile bucket histogram (no global atomics) -------
__global__ __launch_bounds__(256) void binA_kernel(const int* __restrict__ dst,
                                                   int* __restrict__ tileHist,
                                                   int* __restrict__ nspill, int E)
{
    if (blockIdx.x == 0 && threadIdx.x == 0) nspill[0] = 0;  // consumed 3 kernels later
    __shared__ int h[256];
    int tid = threadIdx.x;
    int t = blockIdx.x;
    h[tid] = 0;
    __syncthreads();
    int e0 = t * TILE + tid * EPT;
    if (e0 + EPT <= E) {
        const int4* dp = (const int4*)(dst + e0);
        int4 a = dp[0], b = dp[1];
        atomicAdd(&h[a.x >> BSH], 1); atomicAdd(&h[a.y >> BSH], 1);
        atomicAdd(&h[a.z >> BSH], 1); atomicAdd(&h[a.w >> BSH], 1);
        atomicAdd(&h[b.x >> BSH], 1); atomicAdd(&h[b.y >> BSH], 1);
        atomicAdd(&h[b.z >> BSH], 1); atomicAdd(&h[b.w >> BSH], 1);
    } else {
        for (int k = e0; k < E && k < e0 + EPT; ++k) atomicAdd(&h[dst[k] >> BSH], 1);
    }
    __syncthreads();
    tileHist[t * 256 + tid] = h[tid];
}

// ---------------- binB: per-bucket exclusive scan over tiles (in place) -----
__global__ __launch_bounds__(256) void binB_kernel(int* __restrict__ tileHist,
                                                   int* __restrict__ totals, int NT)
{
    __shared__ int sm[256];
    int b = blockIdx.x, tid = threadIdx.x;
    int C = (NT + 255) / 256;
    int vals[8];
    int s = 0;
    for (int k = 0; k < C; ++k) {
        int t = tid * C + k;
        vals[k] = (t < NT) ? tileHist[t * 256 + b] : 0;
        s += vals[k];
    }
    sm[tid] = s;
    __syncthreads();
    for (int d = 1; d < 256; d <<= 1) {
        int v = (tid >= d) ? sm[tid - d] : 0;
        __syncthreads();
        sm[tid] += v;
        __syncthreads();
    }
    int off = (tid > 0) ? sm[tid - 1] : 0;
    for (int k = 0; k < C; ++k) {
        int t = tid * C + k;
        if (t < NT) { tileHist[t * 256 + b] = off; off += vals[k]; }
    }
    if (tid == 255) totals[b] = sm[255];
}

// ---------------- binC: scatter packed (src<<9|dl); totals-scan done in LDS -
__global__ __launch_bounds__(256) void binC_kernel(const int* __restrict__ src,
                                                   const int* __restrict__ dst,
                                                   const int* __restrict__ tileBase,
                                                   const int* __restrict__ totals,
                                                   int* __restrict__ sorted, int E, int NB)
{
    __shared__ int sm[256];
    __shared__ int cur[256];
    int tid = threadIdx.x;
    int t = blockIdx.x;
    sm[tid] = (tid < NB) ? totals[tid] : 0;
    __syncthreads();
    for (int d = 1; d < 256; d <<= 1) {
        int v = (tid >= d) ? sm[tid - d] : 0;
        __syncthreads();
        sm[tid] += v;
        __syncthreads();
    }
    int bb = (tid > 0) ? sm[tid - 1] : 0;   // exclusive bucket base
    cur[tid] = (tid < NB) ? bb + tileBase[t * 256 + tid] : 0;
    __syncthreads();
    int e0 = t * TILE + tid * EPT;
    int s[EPT], d[EPT];
    int nk = 0;
    if (e0 + EPT <= E) {
        const int4* sp = (const int4*)(src + e0);
        const int4* dp = (const int4*)(dst + e0);
        int4 a = sp[0], b = sp[1], c = dp[0], f = dp[1];
        s[0]=a.x; s[1]=a.y; s[2]=a.z; s[3]=a.w; s[4]=b.x; s[5]=b.y; s[6]=b.z; s[7]=b.w;
        d[0]=c.x; d[1]=c.y; d[2]=c.z; d[3]=c.w; d[4]=f.x; d[5]=f.y; d[6]=f.z; d[7]=f.w;
        nk = EPT;
    } else {
        for (int k = 0; e0 + k < E && k < EPT; ++k) { s[k] = src[e0+k]; d[k] = dst[e0+k]; nk++; }
    }
    for (int k = 0; k < nk; ++k) {
        int p = d[k] >> BSH;
        int pos = atomicAdd(&cur[p], 1);       // LDS atomic; global position is exact
        sorted[pos] = (s[k] << BSH) | (d[k] & (BKT - 1));
    }
}

// ---------------- binD: bucket-local fill; totals-scan in LDS ---------------
__global__ __launch_bounds__(256) void binD_kernel(const int* __restrict__ sorted,
                                                   const int* __restrict__ totals,
                                                   int* __restrict__ bucket,
                                                   int* __restrict__ cnt,
                                                   int* __restrict__ spill,
                                                   int* __restrict__ nspill, int N, int NB)
{
    __shared__ int sm[256];
    __shared__ int lc[BKT];
    int b = blockIdx.x, tid = threadIdx.x;
    sm[tid] = (tid < NB) ? totals[tid] : 0;
    lc[tid] = 0; lc[tid + 256] = 0;
    __syncthreads();
    for (int d = 1; d < 256; d <<= 1) {
        int v = (tid >= d) ? sm[tid - d] : 0;
        __syncthreads();
        sm[tid] += v;
        __syncthreads();
    }
    int beg = (b > 0) ? sm[b - 1] : 0;
    int end = sm[b];
    int nbase = b << BSH;
    for (int i = beg + tid; i < end; i += 256) {
        int v = sorted[i];
        int sv = v >> BSH;
        int dl = v & (BKT - 1);
        int pos = atomicAdd(&lc[dl], 1);
        if (pos < CAP) {
            bucket[(size_t)(nbase + dl) * CAP + pos] = sv;
        } else {                                  // statistically never
            int sp = atomicAdd(nspill, 1);
            if (sp < SPILLMAX) { spill[2*sp] = nbase + dl; spill[2*sp+1] = sv; }
        }
    }
    __syncthreads();
    int n0 = nbase + tid;
    if (n0 < N) cnt[n0] = lc[tid];
    int n1 = nbase + 256 + tid;
    if (n1 < N) cnt[n1] = lc[256 + tid];
}

// ---------------- aggregate: half-wave per node; unroll-8 + int4 list loads -
__global__ __launch_bounds__(256) void agg_kernel(const __half* __restrict__ xh,
                                                  const int* __restrict__ bucket,
                                                  const int* __restrict__ cnt,
                                                  const int* __restrict__ spill,
                                                  const int* __restrict__ nspill,
                                                  __half* __restrict__ aggh, int N)
{
    int node = (blockIdx.x * blockDim.x + threadIdx.x) >> 5;
    int sl = threadIdx.x & 31;
    if (node >= N) return;
    int c = cnt[node];
    int m = (c < CAP) ? c : CAP;
    const int* bp = bucket + (size_t)node * CAP;
    float ax0 = 0, ay0 = 0, ax1 = 0, ay1 = 0, ax2 = 0, ay2 = 0, ax3 = 0, ay3 = 0;
    int j = 0;
    for (; j + 8 <= m; j += 8) {                 // 8 gathers in flight
        int4 va = *(const int4*)(bp + j);
        int4 vb = *(const int4*)(bp + j + 4);
        float2 f0 = __half22float2(*(const __half2*)(xh + (size_t)va.x * CH + sl * 2));
        float2 f1 = __half22float2(*(const __half2*)(xh + (size_t)va.y * CH + sl * 2));
        float2 f2 = __half22float2(*(const __half2*)(xh + (size_t)va.z * CH + sl * 2));
        float2 f3 = __half22float2(*(const __half2*)(xh + (size_t)va.w * CH + sl * 2));
        float2 f4 = __half22float2(*(const __half2*)(xh + (size_t)vb.x * CH + sl * 2));
        float2 f5 = __half22float2(*(const __half2*)(xh + (size_t)vb.y * CH + sl * 2));
        float2 f6 = __half22float2(*(const __half2*)(xh + (size_t)vb.z * CH + sl * 2));
        float2 f7 = __half22float2(*(const __half2*)(xh + (size_t)vb.w * CH + sl * 2));
        ax0 += f0.x + f4.x; ay0 += f0.y + f4.y;
        ax1 += f1.x + f5.x; ay1 += f1.y + f5.y;
        ax2 += f2.x + f6.x; ay2 += f2.y + f6.y;
        ax3 += f3.x + f7.x; ay3 += f3.y + f7.y;
    }
    for (; j + 4 <= m; j += 4) {
        int4 va = *(const int4*)(bp + j);
        float2 f0 = __half22float2(*(const __half2*)(xh + (size_t)va.x * CH + sl * 2));
        float2 f1 = __half22float2(*(const __half2*)(xh + (size_t)va.y * CH + sl * 2));
        float2 f2 = __half22float2(*(const __half2*)(xh + (size_t)va.z * CH + sl * 2));
        float2 f3 = __half22float2(*(const __half2*)(xh + (size_t)va.w * CH + sl * 2));
        ax0 += f0.x; ay0 += f0.y;
        ax1 += f1.x; ay1 += f1.y;
        ax2 += f2.x; ay2 += f2.y;
        ax3 += f3.x; ay3 += f3.y;
    }
    for (; j < m; ++j) {
        float2 f = __half22float2(*(const __half2*)(xh + (size_t)bp[j] * CH + sl * 2));
        ax0 += f.x; ay0 += f.y;
    }
    if (c > CAP) {   // cold spill sweep
        int ns = *nspill;
        if (ns > SPILLMAX) ns = SPILLMAX;
        for (int i = 0; i < ns; ++i) {
            if (spill[2 * i] == node) {
                float2 f = __half22float2(*(const __half2*)(xh + (size_t)spill[2 * i + 1] * CH + sl * 2));
                ax0 += f.x; ay0 += f.y;
            }
        }
    }
    float nd = (c > 0) ? rsqrtf((float)c) : 0.0f;
    float rx = ((ax0 + ax1) + (ax2 + ax3)) * nd;
    float ry = ((ay0 + ay1) + (ay2 + ay3)) * nd;
    *(__half2*)(aggh + (size_t)node * CH + sl * 2) = __floats2half2_rn(rx, ry);
}

// ---------------- out = aggh @ W + bias -------------------------------------
// Wave = 64 rows x one 16-ch quarter (quarter is wave-uniform -> W/bias s_load).
// 4x the waves of the half-split version: 24 waves/CU, hides aggh load latency.
__global__ __launch_bounds__(256) void gemm_out_kernel(const __half* __restrict__ aggh,
                                                       const float* __restrict__ W,
                                                       const float* __restrict__ bias,
                                                       float* __restrict__ out, int N)
{
    int g = blockIdx.x * 256 + threadIdx.x;
    int waveId = __builtin_amdgcn_readfirstlane(g >> 6);   // wave-uniform by construction
    int lane = threadIdx.x & 63;
    int quarter = waveId & 3;
    int row = ((waveId >> 2) << 6) + lane;
    if (row >= N) return;
    const int cbase = quarter * 16;                         // scalar
    float acc[16];
    #pragma unroll
    for (int i = 0; i < 16; ++i) acc[i] = 0.0f;
    const __half* xp = aggh + (size_t)row * CH;
    for (int k0 = 0; k0 < CH; k0 += 8) {
        uint4 u = *(const uint4*)(xp + k0);                 // 8 halves, one 16B load
        const __half2* hp = (const __half2*)&u;
        float xk[8];
        #pragma unroll
        for (int j = 0; j < 4; ++j) {
            float2 f = __half22float2(hp[j]);
            xk[2 * j] = f.x; xk[2 * j + 1] = f.y;
        }
        #pragma unroll
        for (int kk = 0; kk < 8; ++kk) {
            const float* wrow = W + (k0 + kk) * CH + cbase; // wave-uniform -> s_load
            #pragma unroll
            for (int q = 0; q < 4; ++q) {
                float4 w = *(const float4*)(wrow + q * 4);
                acc[q * 4 + 0] += xk[kk] * w.x;
                acc[q * 4 + 1] += xk[kk] * w.y;
                acc[q * 4 + 2] += xk[kk] * w.z;
                acc[q * 4 + 3] += xk[kk] * w.w;
            }
        }
    }
    float* op = out + (size_t)row * CH + cbase;
    #pragma unroll
    for (int q = 0; q < 4; ++q) {
        float4 b = *(const float4*)(bias + cbase + q * 4);  // wave-uniform
        float4 o;
        o.x = acc[q * 4 + 0] + b.x;
        o.y = acc[q * 4 + 1] + b.y;
        o.z = acc[q * 4 + 2] + b.z;
        o.w = acc[q * 4 + 3] + b.w;
        *(float4*)(op + q * 4) = o;                          // 64B contiguous per lane
    }
}

extern "C" void kernel_launch(void* const* d_in, const int* in_sizes, int n_in,
                              void* d_out, int out_size, void* d_ws, size_t ws_size,
                              hipStream_t stream)
{
    const float* x    = (const float*)d_in[0];
    const int*   edge = (const int*)d_in[1];
    const float* W    = (const float*)d_in[2];
    const float* bias = (const float*)d_in[3];
    float* out = (float*)d_out;

    int N = in_sizes[0] / CH;   // 100000
    int E = in_sizes[1] / 2;    // 1280000
    const int* src = edge;
    const int* dst = edge + E;
    int R  = (N + RANGE - 1) / RANGE;        // 8
    int NT = (E + TILE - 1) / TILE;          // 625
    int NB = (N + BKT - 1) >> BSH;           // 196

    // workspace (ints 4B unless noted):
    // [nspill 64][spill 2*SPILLMAX][cnt N][bucket N*CAP]
    // [partial u16 SLICES*R*RANGE ~12.8MB — REUSED after rpscale as:
    //     tileHist NT*256 | totals 256 | sorted E ]
    // [align][xh N*CH halves][align][aggh N*CH halves]
    int* nspill  = (int*)d_ws;
    int* spill   = nspill + 64;
    int* cnt     = spill + 2 * SPILLMAX;
    int* bucket  = cnt + N;
    unsigned short* partial = (unsigned short*)(bucket + (size_t)N * CAP);
    // overlay inside partial (dead after rpscale):
    int* tileHist = (int*)partial;
    int* totals   = tileHist + NT * 256;
    int* sorted   = totals + 320;
    size_t psz = (size_t)SLICES * R * RANGE * sizeof(unsigned short);
    size_t osz = (size_t)(NT * 256 + 320 + E) * sizeof(int);
    size_t xoff = ((((char*)partial - (char*)d_ws) + (psz > osz ? psz : osz)) + 255) & ~(size_t)255;
    __half* xh = (__half*)((char*)d_ws + xoff);
    size_t aoff = ((xoff + (size_t)N * CH * sizeof(__half)) + 255) & ~(size_t)255;
    __half* aggh = (__half*)((char*)d_ws + aoff);

    // chain 1: outdeg hist -> fused reduce+prescale (partial freed after)
    hist_kernel<<<R * SLICES, 256, 0, stream>>>(src, partial, E, N, R);
    rpscale_kernel<<<(N + 255) / 256, 256, 0, stream>>>(partial, x, xh, N, R);
    // chain 2: no-atomic radix partition -> per-node buckets
    binA_kernel<<<NT, 256, 0, stream>>>(dst, tileHist, nspill, E);
    binB_kernel<<<NB, 256, 0, stream>>>(tileHist, totals, NT);
    binC_kernel<<<NT, 256, 0, stream>>>(src, dst, tileHist, totals, sorted, E, NB);
    binD_kernel<<<NB, 256, 0, stream>>>(sorted, totals, bucket, cnt, spill, nspill, N, NB);
    // aggregate + output GEMM
    agg_kernel<<<((size_t)N * 32 + 255) / 256, 256, 0, stream>>>(xh, bucket, cnt, spill,
                                                                 nspill, aggh, N);
    int nwaves = 4 * ((N + 63) / 64);
    gemm_out_kernel<<<(nwaves + 3) / 4, 256, 0, stream>>>(aggh, W, bias, out, N);
}

// Round 16
// 109.720 us; speedup vs baseline: 7.9052x; 1.0389x over previous
//
#include <hip/hip_runtime.h>
#include <hip/hip_fp16.h>

#define CH 64
#define CAP 32        // per-node bucket row = 128B (2 lines); Poisson(12.8) P(>32) ~ 1e-6
#define SPILLMAX 4096
#define RANGE 12500   // outdeg-histogram bins per block (50 KB LDS)
#define SLICES 64     // 8 ranges x 64 slices = 512 hist blocks
#define TILE 2048     // edges per binA/binC block
#define EPT 8         // edges per thread (256 * 8 = 2048)
#define BSH 9         // 512 dsts per radix bucket
#define BKT 512

// ---------------- K1: fused binA (tiles) + outdeg hist (ranges) -------------
// bid < NT       : binA role — per-tile 256-bin dst-bucket histogram
// bid >= NT      : hist role — LDS-privatized src histogram (range, slice)
__global__ __launch_bounds__(256) void histA_kernel(const int* __restrict__ src,
                                                    const int* __restrict__ dst,
                                                    unsigned short* __restrict__ partial,
                                                    int* __restrict__ tileHist,
                                                    int* __restrict__ nspill,
                                                    int E, int N, int R, int NT)
{
    __shared__ int h[RANGE];
    int tid = threadIdx.x;
    int bid = blockIdx.x;
    if (bid < NT) {
        // ---- binA role ----
        if (bid == 0 && tid == 0) nspill[0] = 0;   // consumed by binD, 3 kernels later
        h[tid] = 0;
        __syncthreads();
        int e0 = bid * TILE + tid * EPT;
        if (e0 + EPT <= E) {
            const int4* dp = (const int4*)(dst + e0);
            int4 a = dp[0], b = dp[1];
            atomicAdd(&h[a.x >> BSH], 1); atomicAdd(&h[a.y >> BSH], 1);
            atomicAdd(&h[a.z >> BSH], 1); atomicAdd(&h[a.w >> BSH], 1);
            atomicAdd(&h[b.x >> BSH], 1); atomicAdd(&h[b.y >> BSH], 1);
            atomicAdd(&h[b.z >> BSH], 1); atomicAdd(&h[b.w >> BSH], 1);
        } else {
            for (int k = e0; k < E && k < e0 + EPT; ++k) atomicAdd(&h[dst[k] >> BSH], 1);
        }
        __syncthreads();
        tileHist[bid * 256 + tid] = h[tid];
    } else {
        // ---- hist role ----
        int hb = bid - NT;
        int r  = hb % R;
        int sl = hb / R;
        int lo = r * RANGE;
        int hi = min(lo + RANGE, N);
        int span = hi - lo;
        for (int i = tid; i < span; i += 256) h[i] = 0;
        __syncthreads();
        int per = (E + SLICES - 1) / SLICES;
        int sb = sl * per, se = min(sb + per, E);
        for (int e = sb + tid * 4; e < se; e += 256 * 4) {
            if (e + 4 <= se) {
                int4 v = *(const int4*)(src + e);
                if (v.x >= lo && v.x < hi) atomicAdd(&h[v.x - lo], 1);
                if (v.y >= lo && v.y < hi) atomicAdd(&h[v.y - lo], 1);
                if (v.z >= lo && v.z < hi) atomicAdd(&h[v.z - lo], 1);
                if (v.w >= lo && v.w < hi) atomicAdd(&h[v.w - lo], 1);
            } else {
                for (int k = e; k < se; ++k) {
                    int sv = src[k];
                    if (sv >= lo && sv < hi) atomicAdd(&h[sv - lo], 1);
                }
            }
        }
        __syncthreads();
        unsigned short* pp = partial + (size_t)hb * RANGE;
        for (int i = tid; i < span; i += 256) pp[i] = (unsigned short)h[i];
    }
}

// ---------------- K2: fused rpscale (nodes) + binB (bucket scans) -----------
// bid < NPB : rpscale role — outdeg reduce + xh = rsqrt(od)*x (fp16)
// bid >= NPB: binB role — per-bucket exclusive scan over tiles
__global__ __launch_bounds__(256) void rpscaleB_kernel(const unsigned short* __restrict__ partial,
                                                       const float* __restrict__ x,
                                                       __half* __restrict__ xh,
                                                       int* __restrict__ tileHist,
                                                       int* __restrict__ totals,
                                                       int N, int R, int NT, int NPB)
{
    __shared__ float nsl[256];
    __shared__ int sm[256];
    int tid = threadIdx.x;
    int bid = blockIdx.x;
    if (bid < NPB) {
        // ---- rpscale role ----
        int n0 = bid * 256;
        int n = n0 + tid;
        if (n < N) {
            int r = n / RANGE, off = n - r * RANGE;
            int s = 0;
            #pragma unroll 8
            for (int sl = 0; sl < SLICES; ++sl)
                s += partial[(size_t)(sl * R + r) * RANGE + off];
            nsl[tid] = (s > 0) ? rsqrtf((float)s) : 0.0f;
        } else {
            nsl[tid] = 0.0f;
        }
        __syncthreads();
        int sub = tid & 7;
        int nl0 = tid >> 3;
        for (int p = 0; p < 8; ++p) {
            int nl = p * 32 + nl0;
            int node = n0 + nl;
            if (node >= N) break;
            float ns = nsl[nl];
            const float4* xp = (const float4*)(x + (size_t)node * CH + sub * 8);
            float4 a = xp[0], b = xp[1];
            __half2 h0 = __floats2half2_rn(a.x * ns, a.y * ns);
            __half2 h1 = __floats2half2_rn(a.z * ns, a.w * ns);
            __half2 h2 = __floats2half2_rn(b.x * ns, b.y * ns);
            __half2 h3 = __floats2half2_rn(b.z * ns, b.w * ns);
            uint4 u;
            u.x = (unsigned)__half_as_ushort(h0.x) | ((unsigned)__half_as_ushort(h0.y) << 16);
            u.y = (unsigned)__half_as_ushort(h1.x) | ((unsigned)__half_as_ushort(h1.y) << 16);
            u.z = (unsigned)__half_as_ushort(h2.x) | ((unsigned)__half_as_ushort(h2.y) << 16);
            u.w = (unsigned)__half_as_ushort(h3.x) | ((unsigned)__half_as_ushort(h3.y) << 16);
            *(uint4*)(xh + (size_t)node * CH + sub * 8) = u;
        }
    } else {
        // ---- binB role ----
        int b = bid - NPB;
        int C = (NT + 255) / 256;
        int vals[8];
        int s = 0;
        for (int k = 0; k < C; ++k) {
            int t = tid * C + k;
            vals[k] = (t < NT) ? tileHist[t * 256 + b] : 0;
            s += vals[k];
        }
        sm[tid] = s;
        __syncthreads();
        for (int d = 1; d < 256; d <<= 1) {
            int v = (tid >= d) ? sm[tid - d] : 0;
            __syncthreads();
            sm[tid] += v;
            __syncthreads();
        }
        int off = (tid > 0) ? sm[tid - 1] : 0;
        for (int k = 0; k < C; ++k) {
            int t = tid * C + k;
            if (t < NT) { tileHist[t * 256 + b] = off; off += vals[k]; }
        }
        if (tid == 255) totals[b] = sm[255];
    }
}

// ---------------- binC: scatter packed (src<<9|dl); totals-scan done in LDS -
__global__ __launch_bounds__(256) void binC_kernel(const int* __restrict__ src,
                                                   const int* __restrict__ dst,
                                                   const int* __restrict__ tileBase,
                                                   const int* __restrict__ totals,
                                                   int* __restrict__ sorted, int E, int NB)
{
    __shared__ int sm[256];
    __shared__ int cur[256];
    int tid = threadIdx.x;
    int t = blockIdx.x;
    sm[tid] = (tid < NB) ? totals[tid] : 0;
    __syncthreads();
    for (int d = 1; d < 256; d <<= 1) {
        int v = (tid >= d) ? sm[tid - d] : 0;
        __syncthreads();
        sm[tid] += v;
        __syncthreads();
    }
    int bb = (tid > 0) ? sm[tid - 1] : 0;   // exclusive bucket base
    cur[tid] = (tid < NB) ? bb + tileBase[t * 256 + tid] : 0;
    __syncthreads();
    int e0 = t * TILE + tid * EPT;
    int s[EPT], d[EPT];
    int nk = 0;
    if (e0 + EPT <= E) {
        const int4* sp = (const int4*)(src + e0);
        const int4* dp = (const int4*)(dst + e0);
        int4 a = sp[0], b = sp[1], c = dp[0], f = dp[1];
        s[0]=a.x; s[1]=a.y; s[2]=a.z; s[3]=a.w; s[4]=b.x; s[5]=b.y; s[6]=b.z; s[7]=b.w;
        d[0]=c.x; d[1]=c.y; d[2]=c.z; d[3]=c.w; d[4]=f.x; d[5]=f.y; d[6]=f.z; d[7]=f.w;
        nk = EPT;
    } else {
        for (int k = 0; e0 + k < E && k < EPT; ++k) { s[k] = src[e0+k]; d[k] = dst[e0+k]; nk++; }
    }
    for (int k = 0; k < nk; ++k) {
        int p = d[k] >> BSH;
        int pos = atomicAdd(&cur[p], 1);       // LDS atomic; global position is exact
        sorted[pos] = (s[k] << BSH) | (d[k] & (BKT - 1));
    }
}

// ---------------- binD: bucket-local fill; totals-scan in LDS ---------------
__global__ __launch_bounds__(256) void binD_kernel(const int* __restrict__ sorted,
                                                   const int* __restrict__ totals,
                                                   int* __restrict__ bucket,
                                                   int* __restrict__ cnt,
                                                   int* __restrict__ spill,
                                                   int* __restrict__ nspill, int N, int NB)
{
    __shared__ int sm[256];
    __shared__ int lc[BKT];
    int b = blockIdx.x, tid = threadIdx.x;
    sm[tid] = (tid < NB) ? totals[tid] : 0;
    lc[tid] = 0; lc[tid + 256] = 0;
    __syncthreads();
    for (int d = 1; d < 256; d <<= 1) {
        int v = (tid >= d) ? sm[tid - d] : 0;
        __syncthreads();
        sm[tid] += v;
        __syncthreads();
    }
    int beg = (b > 0) ? sm[b - 1] : 0;
    int end = sm[b];
    int nbase = b << BSH;
    for (int i = beg + tid; i < end; i += 256) {
        int v = sorted[i];
        int sv = v >> BSH;
        int dl = v & (BKT - 1);
        int pos = atomicAdd(&lc[dl], 1);
        if (pos < CAP) {
            bucket[(size_t)(nbase + dl) * CAP + pos] = sv;
        } else {                                  // statistically never
            int sp = atomicAdd(nspill, 1);
            if (sp < SPILLMAX) { spill[2*sp] = nbase + dl; spill[2*sp+1] = sv; }
        }
    }
    __syncthreads();
    int n0 = nbase + tid;
    if (n0 < N) cnt[n0] = lc[tid];
    int n1 = nbase + 256 + tid;
    if (n1 < N) cnt[n1] = lc[256 + tid];
}

// ---------------- aggregate: half-wave per node; unroll-8 + int4 list loads -
__global__ __launch_bounds__(256) void agg_kernel(const __half* __restrict__ xh,
                                                  const int* __restrict__ bucket,
                                                  const int* __restrict__ cnt,
                                                  const int* __restrict__ spill,
                                                  const int* __restrict__ nspill,
                                                  __half* __restrict__ aggh, int N)
{
    int node = (blockIdx.x * blockDim.x + threadIdx.x) >> 5;
    int sl = threadIdx.x & 31;
    if (node >= N) return;
    int c = cnt[node];
    int m = (c < CAP) ? c : CAP;
    const int* bp = bucket + (size_t)node * CAP;
    float ax0 = 0, ay0 = 0, ax1 = 0, ay1 = 0, ax2 = 0, ay2 = 0, ax3 = 0, ay3 = 0;
    int j = 0;
    for (; j + 8 <= m; j += 8) {                 // 8 gathers in flight
        int4 va = *(const int4*)(bp + j);
        int4 vb = *(const int4*)(bp + j + 4);
        float2 f0 = __half22float2(*(const __half2*)(xh + (size_t)va.x * CH + sl * 2));
        float2 f1 = __half22float2(*(const __half2*)(xh + (size_t)va.y * CH + sl * 2));
        float2 f2 = __half22float2(*(const __half2*)(xh + (size_t)va.z * CH + sl * 2));
        float2 f3 = __half22float2(*(const __half2*)(xh + (size_t)va.w * CH + sl * 2));
        float2 f4 = __half22float2(*(const __half2*)(xh + (size_t)vb.x * CH + sl * 2));
        float2 f5 = __half22float2(*(const __half2*)(xh + (size_t)vb.y * CH + sl * 2));
        float2 f6 = __half22float2(*(const __half2*)(xh + (size_t)vb.z * CH + sl * 2));
        float2 f7 = __half22float2(*(const __half2*)(xh + (size_t)vb.w * CH + sl * 2));
        ax0 += f0.x + f4.x; ay0 += f0.y + f4.y;
        ax1 += f1.x + f5.x; ay1 += f1.y + f5.y;
        ax2 += f2.x + f6.x; ay2 += f2.y + f6.y;
        ax3 += f3.x + f7.x; ay3 += f3.y + f7.y;
    }
    for (; j + 4 <= m; j += 4) {
        int4 va = *(const int4*)(bp + j);
        float2 f0 = __half22float2(*(const __half2*)(xh + (size_t)va.x * CH + sl * 2));
        float2 f1 = __half22float2(*(const __half2*)(xh + (size_t)va.y * CH + sl * 2));
        float2 f2 = __half22float2(*(const __half2*)(xh + (size_t)va.z * CH + sl * 2));
        float2 f3 = __half22float2(*(const __half2*)(xh + (size_t)va.w * CH + sl * 2));
        ax0 += f0.x; ay0 += f0.y;
        ax1 += f1.x; ay1 += f1.y;
        ax2 += f2.x; ay2 += f2.y;
        ax3 += f3.x; ay3 += f3.y;
    }
    for (; j < m; ++j) {
        float2 f = __half22float2(*(const __half2*)(xh + (size_t)bp[j] * CH + sl * 2));
        ax0 += f.x; ay0 += f.y;
    }
    if (c > CAP) {   // cold spill sweep
        int ns = *nspill;
        if (ns > SPILLMAX) ns = SPILLMAX;
        for (int i = 0; i < ns; ++i) {
            if (spill[2 * i] == node) {
                float2 f = __half22float2(*(const __half2*)(xh + (size_t)spill[2 * i + 1] * CH + sl * 2));
                ax0 += f.x; ay0 += f.y;
            }
        }
    }
    float nd = (c > 0) ? rsqrtf((float)c) : 0.0f;
    float rx = ((ax0 + ax1) + (ax2 + ax3)) * nd;
    float ry = ((ay0 + ay1) + (ay2 + ay3)) * nd;
    *(__half2*)(aggh + (size_t)node * CH + sl * 2) = __floats2half2_rn(rx, ry);
}

// ---------------- out = aggh @ W + bias -------------------------------------
// Wave = 64 rows x one 16-ch quarter (quarter is wave-uniform -> W/bias s_load).
__global__ __launch_bounds__(256) void gemm_out_kernel(const __half* __restrict__ aggh,
                                                       const float* __restrict__ W,
                                                       const float* __restrict__ bias,
                                                       float* __restrict__ out, int N)
{
    int g = blockIdx.x * 256 + threadIdx.x;
    int waveId = __builtin_amdgcn_readfirstlane(g >> 6);   // wave-uniform by construction
    int lane = threadIdx.x & 63;
    int quarter = waveId & 3;
    int row = ((waveId >> 2) << 6) + lane;
    if (row >= N) return;
    const int cbase = quarter * 16;                         // scalar
    float acc[16];
    #pragma unroll
    for (int i = 0; i < 16; ++i) acc[i] = 0.0f;
    const __half* xp = aggh + (size_t)row * CH;
    for (int k0 = 0; k0 < CH; k0 += 8) {
        uint4 u = *(const uint4*)(xp + k0);                 // 8 halves, one 16B load
        const __half2* hp = (const __half2*)&u;
        float xk[8];
        #pragma unroll
        for (int j = 0; j < 4; ++j) {
            float2 f = __half22float2(hp[j]);
            xk[2 * j] = f.x; xk[2 * j + 1] = f.y;
        }
        #pragma unroll
        for (int kk = 0; kk < 8; ++kk) {
            const float* wrow = W + (k0 + kk) * CH + cbase; // wave-uniform -> s_load
            #pragma unroll
            for (int q = 0; q < 4; ++q) {
                float4 w = *(const float4*)(wrow + q * 4);
                acc[q * 4 + 0] += xk[kk] * w.x;
                acc[q * 4 + 1] += xk[kk] * w.y;
                acc[q * 4 + 2] += xk[kk] * w.z;
                acc[q * 4 + 3] += xk[kk] * w.w;
            }
        }
    }
    float* op = out + (size_t)row * CH + cbase;
    #pragma unroll
    for (int q = 0; q < 4; ++q) {
        float4 b = *(const float4*)(bias + cbase + q * 4);  // wave-uniform
        float4 o;
        o.x = acc[q * 4 + 0] + b.x;
        o.y = acc[q * 4 + 1] + b.y;
        o.z = acc[q * 4 + 2] + b.z;
        o.w = acc[q * 4 + 3] + b.w;
        *(float4*)(op + q * 4) = o;                          // 64B contiguous per lane
    }
}

extern "C" void kernel_launch(void* const* d_in, const int* in_sizes, int n_in,
                              void* d_out, int out_size, void* d_ws, size_t ws_size,
                              hipStream_t stream)
{
    const float* x    = (const float*)d_in[0];
    const int*   edge = (const int*)d_in[1];
    const float* W    = (const float*)d_in[2];
    const float* bias = (const float*)d_in[3];
    float* out = (float*)d_out;

    int N = in_sizes[0] / CH;   // 100000
    int E = in_sizes[1] / 2;    // 1280000
    const int* src = edge;
    const int* dst = edge + E;
    int R   = (N + RANGE - 1) / RANGE;        // 8
    int NT  = (E + TILE - 1) / TILE;          // 625
    int NB  = (N + BKT - 1) >> BSH;           // 196
    int NPB = (N + 255) / 256;                // 391

    // workspace (ints 4B unless noted):
    // [nspill 64][spill 2*SPILLMAX][cnt N][bucket N*CAP]
    // [partial u16 SLICES*R*RANGE ~12.8MB — REUSED after rpscaleB as:
    //     tileHist NT*256 | totals 320 | sorted E ]
    // [align][xh N*CH halves][align][aggh N*CH halves]
    int* nspill  = (int*)d_ws;
    int* spill   = nspill + 64;
    int* cnt     = spill + 2 * SPILLMAX;
    int* bucket  = cnt + N;
    unsigned short* partial = (unsigned short*)(bucket + (size_t)N * CAP);
    // overlay AFTER partial (tileHist/totals live concurrently with partial;
    // sorted overwrites partial only after rpscaleB consumed it)
    int* tileHist = (int*)(partial + (size_t)SLICES * R * RANGE);
    int* totals   = tileHist + NT * 256;
    int* sorted   = (int*)partial;            // written by binC (after rpscaleB)
    size_t endoff = (char*)(totals + 320) - (char*)d_ws;
    size_t xoff = (endoff + 255) & ~(size_t)255;
    __half* xh = (__half*)((char*)d_ws + xoff);
    size_t aoff = ((xoff + (size_t)N * CH * sizeof(__half)) + 255) & ~(size_t)255;
    __half* aggh = (__half*)((char*)d_ws + aoff);

    // K1: binA tiles (bid<NT) + outdeg hist (bid>=NT); also zeroes nspill
    histA_kernel<<<NT + R * SLICES, 256, 0, stream>>>(src, dst, partial, tileHist,
                                                      nspill, E, N, R, NT);
    // K2: rpscale (bid<NPB) + binB bucket scans (bid>=NPB)
    rpscaleB_kernel<<<NPB + NB, 256, 0, stream>>>(partial, x, xh, tileHist, totals,
                                                  N, R, NT, NPB);
    // binC overwrites partial with sorted (partial is dead after K2)
    binC_kernel<<<NT, 256, 0, stream>>>(src, dst, tileHist, totals, sorted, E, NB);
    binD_kernel<<<NB, 256, 0, stream>>>(sorted, totals, bucket, cnt, spill, nspill, N, NB);
    agg_kernel<<<((size_t)N * 32 + 255) / 256, 256, 0, stream>>>(xh, bucket, cnt, spill,
                                                                 nspill, aggh, N);
    int nwaves = 4 * ((N + 63) / 64);
    gemm_out_kernel<<<(nwaves + 3) / 4, 256, 0, stream>>>(aggh, W, bias, out, N);
}

// Round 17
// 109.000 us; speedup vs baseline: 7.9574x; 1.0066x over previous
//
#include <hip/hip_runtime.h>
#include <hip/hip_fp16.h>

#define CH 64
#define CAP 32        // per-node bucket row = 128B (2 lines); Poisson(12.8) P(>32) ~ 1e-6
#define SPILLMAX 4096
#define RANGE 12500   // outdeg-histogram bins per block (50 KB LDS)
#define SLICES 64     // 8 ranges x 64 slices = 512 hist blocks
#define TILE 2048     // edges per binA/binC block
#define EPT 8         // edges per thread (256 * 8 = 2048)
#define BSH 9         // 512 dsts per radix bucket
#define BKT 512

// ---------------- K1: fused binA (tiles) + outdeg hist (ranges) -------------
__global__ __launch_bounds__(256) void histA_kernel(const int* __restrict__ src,
                                                    const int* __restrict__ dst,
                                                    unsigned short* __restrict__ partial,
                                                    int* __restrict__ tileHist,
                                                    int* __restrict__ nspill,
                                                    int E, int N, int R, int NT)
{
    __shared__ int h[RANGE];
    int tid = threadIdx.x;
    int bid = blockIdx.x;
    if (bid < NT) {
        // ---- binA role ----
        if (bid == 0 && tid == 0) nspill[0] = 0;   // consumed by binD, 3 kernels later
        h[tid] = 0;
        __syncthreads();
        int e0 = bid * TILE + tid * EPT;
        if (e0 + EPT <= E) {
            const int4* dp = (const int4*)(dst + e0);
            int4 a = dp[0], b = dp[1];
            atomicAdd(&h[a.x >> BSH], 1); atomicAdd(&h[a.y >> BSH], 1);
            atomicAdd(&h[a.z >> BSH], 1); atomicAdd(&h[a.w >> BSH], 1);
            atomicAdd(&h[b.x >> BSH], 1); atomicAdd(&h[b.y >> BSH], 1);
            atomicAdd(&h[b.z >> BSH], 1); atomicAdd(&h[b.w >> BSH], 1);
        } else {
            for (int k = e0; k < E && k < e0 + EPT; ++k) atomicAdd(&h[dst[k] >> BSH], 1);
        }
        __syncthreads();
        tileHist[bid * 256 + tid] = h[tid];
    } else {
        // ---- hist role ----
        int hb = bid - NT;
        int r  = hb % R;
        int sl = hb / R;
        int lo = r * RANGE;
        int hi = min(lo + RANGE, N);
        int span = hi - lo;
        for (int i = tid; i < span; i += 256) h[i] = 0;
        __syncthreads();
        int per = (E + SLICES - 1) / SLICES;
        int sb = sl * per, se = min(sb + per, E);
        for (int e = sb + tid * 4; e < se; e += 256 * 4) {
            if (e + 4 <= se) {
                int4 v = *(const int4*)(src + e);
                if (v.x >= lo && v.x < hi) atomicAdd(&h[v.x - lo], 1);
                if (v.y >= lo && v.y < hi) atomicAdd(&h[v.y - lo], 1);
                if (v.z >= lo && v.z < hi) atomicAdd(&h[v.z - lo], 1);
                if (v.w >= lo && v.w < hi) atomicAdd(&h[v.w - lo], 1);
            } else {
                for (int k = e; k < se; ++k) {
                    int sv = src[k];
                    if (sv >= lo && sv < hi) atomicAdd(&h[sv - lo], 1);
                }
            }
        }
        __syncthreads();
        unsigned short* pp = partial + (size_t)hb * RANGE;
        for (int i = tid; i < span; i += 256) pp[i] = (unsigned short)h[i];
    }
}

// ---------------- K2: fused rpscale (nodes) + binB (bucket scans) -----------
__global__ __launch_bounds__(256) void rpscaleB_kernel(const unsigned short* __restrict__ partial,
                                                       const float* __restrict__ x,
                                                       __half* __restrict__ xh,
                                                       int* __restrict__ tileHist,
                                                       int* __restrict__ totals,
                                                       int N, int R, int NT, int NPB)
{
    __shared__ float nsl[256];
    __shared__ int sm[256];
    int tid = threadIdx.x;
    int bid = blockIdx.x;
    if (bid < NPB) {
        // ---- rpscale role ----
        int n0 = bid * 256;
        int n = n0 + tid;
        if (n < N) {
            int r = n / RANGE, off = n - r * RANGE;
            int s = 0;
            #pragma unroll 8
            for (int sl = 0; sl < SLICES; ++sl)
                s += partial[(size_t)(sl * R + r) * RANGE + off];
            nsl[tid] = (s > 0) ? rsqrtf((float)s) : 0.0f;
        } else {
            nsl[tid] = 0.0f;
        }
        __syncthreads();
        int sub = tid & 7;
        int nl0 = tid >> 3;
        for (int p = 0; p < 8; ++p) {
            int nl = p * 32 + nl0;
            int node = n0 + nl;
            if (node >= N) break;
            float ns = nsl[nl];
            const float4* xp = (const float4*)(x + (size_t)node * CH + sub * 8);
            float4 a = xp[0], b = xp[1];
            __half2 h0 = __floats2half2_rn(a.x * ns, a.y * ns);
            __half2 h1 = __floats2half2_rn(a.z * ns, a.w * ns);
            __half2 h2 = __floats2half2_rn(b.x * ns, b.y * ns);
            __half2 h3 = __floats2half2_rn(b.z * ns, b.w * ns);
            uint4 u;
            u.x = (unsigned)__half_as_ushort(h0.x) | ((unsigned)__half_as_ushort(h0.y) << 16);
            u.y = (unsigned)__half_as_ushort(h1.x) | ((unsigned)__half_as_ushort(h1.y) << 16);
            u.z = (unsigned)__half_as_ushort(h2.x) | ((unsigned)__half_as_ushort(h2.y) << 16);
            u.w = (unsigned)__half_as_ushort(h3.x) | ((unsigned)__half_as_ushort(h3.y) << 16);
            *(uint4*)(xh + (size_t)node * CH + sub * 8) = u;
        }
    } else {
        // ---- binB role ----
        int b = bid - NPB;
        int C = (NT + 255) / 256;
        int vals[8];
        int s = 0;
        for (int k = 0; k < C; ++k) {
            int t = tid * C + k;
            vals[k] = (t < NT) ? tileHist[t * 256 + b] : 0;
            s += vals[k];
        }
        sm[tid] = s;
        __syncthreads();
        for (int d = 1; d < 256; d <<= 1) {
            int v = (tid >= d) ? sm[tid - d] : 0;
            __syncthreads();
            sm[tid] += v;
            __syncthreads();
        }
        int off = (tid > 0) ? sm[tid - 1] : 0;
        for (int k = 0; k < C; ++k) {
            int t = tid * C + k;
            if (t < NT) { tileHist[t * 256 + b] = off; off += vals[k]; }
        }
        if (tid == 255) totals[b] = sm[255];
    }
}

// ---------------- binC: LDS-staged scatter -> coalesced burst writes --------
// Rank edges into a bucket-ordered 8KB LDS buffer, then drain linearly:
// consecutive threads write consecutive global positions within each run.
__global__ __launch_bounds__(256) void binC_kernel(const int* __restrict__ src,
                                                   const int* __restrict__ dst,
                                                   const int* __restrict__ tileBase,
                                                   const int* __restrict__ totals,
                                                   int* __restrict__ sorted, int E, int NB)
{
    __shared__ int sm[256];     // totals scan -> bucket bases
    __shared__ int gb[256];     // global dest base per bucket for this tile
    __shared__ int lcnt[256];   // block-local per-bucket count / rank cursor
    __shared__ int lbase[256];  // block-local exclusive offsets
    __shared__ int slotVal[TILE];
    int tid = threadIdx.x;
    int t = blockIdx.x;
    sm[tid] = (tid < NB) ? totals[tid] : 0;
    lcnt[tid] = 0;
    __syncthreads();
    for (int d = 1; d < 256; d <<= 1) {
        int v = (tid >= d) ? sm[tid - d] : 0;
        __syncthreads();
        sm[tid] += v;
        __syncthreads();
    }
    int bb = (tid > 0) ? sm[tid - 1] : 0;   // exclusive bucket base
    gb[tid] = (tid < NB) ? bb + tileBase[t * 256 + tid] : 0;
    __syncthreads();
    // load edges, rank within (tile,bucket)
    int e0 = t * TILE + tid * EPT;
    int s[EPT], d[EPT], rk[EPT], pb[EPT];
    int nk = 0;
    if (e0 + EPT <= E) {
        const int4* sp = (const int4*)(src + e0);
        const int4* dp = (const int4*)(dst + e0);
        int4 a = sp[0], b = sp[1], c = dp[0], f = dp[1];
        s[0]=a.x; s[1]=a.y; s[2]=a.z; s[3]=a.w; s[4]=b.x; s[5]=b.y; s[6]=b.z; s[7]=b.w;
        d[0]=c.x; d[1]=c.y; d[2]=c.z; d[3]=c.w; d[4]=f.x; d[5]=f.y; d[6]=f.z; d[7]=f.w;
        nk = EPT;
    } else {
        for (int k = 0; e0 + k < E && k < EPT; ++k) { s[k] = src[e0+k]; d[k] = dst[e0+k]; nk++; }
    }
    for (int k = 0; k < nk; ++k) {
        pb[k] = d[k] >> BSH;
        rk[k] = atomicAdd(&lcnt[pb[k]], 1);
    }
    __syncthreads();
    // exclusive scan of lcnt -> lbase (reuse sm)
    sm[tid] = lcnt[tid];
    __syncthreads();
    for (int dd = 1; dd < 256; dd <<= 1) {
        int v = (tid >= dd) ? sm[tid - dd] : 0;
        __syncthreads();
        sm[tid] += v;
        __syncthreads();
    }
    lbase[tid] = (tid > 0) ? sm[tid - 1] : 0;
    int total = sm[255];   // == edges in this tile
    __syncthreads();
    // place into LDS bucket-ordered
    for (int k = 0; k < nk; ++k)
        slotVal[lbase[pb[k]] + rk[k]] = (s[k] << BSH) | (d[k] & (BKT - 1));
    __syncthreads();
    // drain: slot i -> bucket p via binary search on lbase; burst-coalesced
    for (int i = tid; i < total; i += 256) {
        int lo = 0, hi = 255;            // find largest p with lbase[p] <= i
        #pragma unroll
        for (int st = 0; st < 8; ++st) {
            int mid = (lo + hi + 1) >> 1;
            if (lbase[mid] <= i) lo = mid; else hi = mid - 1;
        }
        sorted[gb[lo] + (i - lbase[lo])] = slotVal[i];
    }
}

// ---------------- binD: bucket-local fill; totals-scan in LDS ---------------
__global__ __launch_bounds__(256) void binD_kernel(const int* __restrict__ sorted,
                                                   const int* __restrict__ totals,
                                                   int* __restrict__ bucket,
                                                   int* __restrict__ cnt,
                                                   int* __restrict__ spill,
                                                   int* __restrict__ nspill, int N, int NB)
{
    __shared__ int sm[256];
    __shared__ int lc[BKT];
    int b = blockIdx.x, tid = threadIdx.x;
    sm[tid] = (tid < NB) ? totals[tid] : 0;
    lc[tid] = 0; lc[tid + 256] = 0;
    __syncthreads();
    for (int d = 1; d < 256; d <<= 1) {
        int v = (tid >= d) ? sm[tid - d] : 0;
        __syncthreads();
        sm[tid] += v;
        __syncthreads();
    }
    int beg = (b > 0) ? sm[b - 1] : 0;
    int end = sm[b];
    int nbase = b << BSH;
    for (int i = beg + tid; i < end; i += 256) {
        int v = sorted[i];
        int sv = v >> BSH;
        int dl = v & (BKT - 1);
        int pos = atomicAdd(&lc[dl], 1);
        if (pos < CAP) {
            bucket[(size_t)(nbase + dl) * CAP + pos] = sv;
        } else {                                  // statistically never
            int sp = atomicAdd(nspill, 1);
            if (sp < SPILLMAX) { spill[2*sp] = nbase + dl; spill[2*sp+1] = sv; }
        }
    }
    __syncthreads();
    int n0 = nbase + tid;
    if (n0 < N) cnt[n0] = lc[tid];
    int n1 = nbase + 256 + tid;
    if (n1 < N) cnt[n1] = lc[256 + tid];
}

// ---------------- aggregate: persistent half-waves, grid-stride nodes -------
// Fixes tail imbalance: each half-wave handles ~N/nHW nodes (variance averages).
__global__ __launch_bounds__(256) void agg_kernel(const __half* __restrict__ xh,
                                                  const int* __restrict__ bucket,
                                                  const int* __restrict__ cnt,
                                                  const int* __restrict__ spill,
                                                  const int* __restrict__ nspill,
                                                  __half* __restrict__ aggh, int N)
{
    int hw0 = (blockIdx.x * blockDim.x + threadIdx.x) >> 5;
    int nHW = (gridDim.x * blockDim.x) >> 5;
    int sl = threadIdx.x & 31;
    for (int node = hw0; node < N; node += nHW) {
        int c = cnt[node];
        int m = (c < CAP) ? c : CAP;
        const int* bp = bucket + (size_t)node * CAP;
        float ax0 = 0, ay0 = 0, ax1 = 0, ay1 = 0, ax2 = 0, ay2 = 0, ax3 = 0, ay3 = 0;
        int j = 0;
        for (; j + 8 <= m; j += 8) {                 // 8 gathers in flight
            int4 va = *(const int4*)(bp + j);
            int4 vb = *(const int4*)(bp + j + 4);
            float2 f0 = __half22float2(*(const __half2*)(xh + (size_t)va.x * CH + sl * 2));
            float2 f1 = __half22float2(*(const __half2*)(xh + (size_t)va.y * CH + sl * 2));
            float2 f2 = __half22float2(*(const __half2*)(xh + (size_t)va.z * CH + sl * 2));
            float2 f3 = __half22float2(*(const __half2*)(xh + (size_t)va.w * CH + sl * 2));
            float2 f4 = __half22float2(*(const __half2*)(xh + (size_t)vb.x * CH + sl * 2));
            float2 f5 = __half22float2(*(const __half2*)(xh + (size_t)vb.y * CH + sl * 2));
            float2 f6 = __half22float2(*(const __half2*)(xh + (size_t)vb.z * CH + sl * 2));
            float2 f7 = __half22float2(*(const __half2*)(xh + (size_t)vb.w * CH + sl * 2));
            ax0 += f0.x + f4.x; ay0 += f0.y + f4.y;
            ax1 += f1.x + f5.x; ay1 += f1.y + f5.y;
            ax2 += f2.x + f6.x; ay2 += f2.y + f6.y;
            ax3 += f3.x + f7.x; ay3 += f3.y + f7.y;
        }
        for (; j + 4 <= m; j += 4) {
            int4 va = *(const int4*)(bp + j);
            float2 f0 = __half22float2(*(const __half2*)(xh + (size_t)va.x * CH + sl * 2));
            float2 f1 = __half22float2(*(const __half2*)(xh + (size_t)va.y * CH + sl * 2));
            float2 f2 = __half22float2(*(const __half2*)(xh + (size_t)va.z * CH + sl * 2));
            float2 f3 = __half22float2(*(const __half2*)(xh + (size_t)va.w * CH + sl * 2));
            ax0 += f0.x; ay0 += f0.y;
            ax1 += f1.x; ay1 += f1.y;
            ax2 += f2.x; ay2 += f2.y;
            ax3 += f3.x; ay3 += f3.y;
        }
        for (; j < m; ++j) {
            float2 f = __half22float2(*(const __half2*)(xh + (size_t)bp[j] * CH + sl * 2));
            ax0 += f.x; ay0 += f.y;
        }
        if (c > CAP) {   // cold spill sweep
            int ns = *nspill;
            if (ns > SPILLMAX) ns = SPILLMAX;
            for (int i = 0; i < ns; ++i) {
                if (spill[2 * i] == node) {
                    float2 f = __half22float2(*(const __half2*)(xh + (size_t)spill[2 * i + 1] * CH + sl * 2));
                    ax0 += f.x; ay0 += f.y;
                }
            }
        }
        float nd = (c > 0) ? rsqrtf((float)c) : 0.0f;
        float rx = ((ax0 + ax1) + (ax2 + ax3)) * nd;
        float ry = ((ay0 + ay1) + (ay2 + ay3)) * nd;
        *(__half2*)(aggh + (size_t)node * CH + sl * 2) = __floats2half2_rn(rx, ry);
    }
}

// ---------------- out = aggh @ W + bias -------------------------------------
// Wave = 64 rows x one 16-ch quarter (quarter is wave-uniform -> W/bias s_load).
__global__ __launch_bounds__(256) void gemm_out_kernel(const __half* __restrict__ aggh,
                                                       const float* __restrict__ W,
                                                       const float* __restrict__ bias,
                                                       float* __restrict__ out, int N)
{
    int g = blockIdx.x * 256 + threadIdx.x;
    int waveId = __builtin_amdgcn_readfirstlane(g >> 6);   // wave-uniform by construction
    int lane = threadIdx.x & 63;
    int quarter = waveId & 3;
    int row = ((waveId >> 2) << 6) + lane;
    if (row >= N) return;
    const int cbase = quarter * 16;                         // scalar
    float acc[16];
    #pragma unroll
    for (int i = 0; i < 16; ++i) acc[i] = 0.0f;
    const __half* xp = aggh + (size_t)row * CH;
    for (int k0 = 0; k0 < CH; k0 += 8) {
        uint4 u = *(const uint4*)(xp + k0);                 // 8 halves, one 16B load
        const __half2* hp = (const __half2*)&u;
        float xk[8];
        #pragma unroll
        for (int j = 0; j < 4; ++j) {
            float2 f = __half22float2(hp[j]);
            xk[2 * j] = f.x; xk[2 * j + 1] = f.y;
        }
        #pragma unroll
        for (int kk = 0; kk < 8; ++kk) {
            const float* wrow = W + (k0 + kk) * CH + cbase; // wave-uniform -> s_load
            #pragma unroll
            for (int q = 0; q < 4; ++q) {
                float4 w = *(const float4*)(wrow + q * 4);
                acc[q * 4 + 0] += xk[kk] * w.x;
                acc[q * 4 + 1] += xk[kk] * w.y;
                acc[q * 4 + 2] += xk[kk] * w.z;
                acc[q * 4 + 3] += xk[kk] * w.w;
            }
        }
    }
    float* op = out + (size_t)row * CH + cbase;
    #pragma unroll
    for (int q = 0; q < 4; ++q) {
        float4 b = *(const float4*)(bias + cbase + q * 4);  // wave-uniform
        float4 o;
        o.x = acc[q * 4 + 0] + b.x;
        o.y = acc[q * 4 + 1] + b.y;
        o.z = acc[q * 4 + 2] + b.z;
        o.w = acc[q * 4 + 3] + b.w;
        *(float4*)(op + q * 4) = o;                          // 64B contiguous per lane
    }
}

extern "C" void kernel_launch(void* const* d_in, const int* in_sizes, int n_in,
                              void* d_out, int out_size, void* d_ws, size_t ws_size,
                              hipStream_t stream)
{
    const float* x    = (const float*)d_in[0];
    const int*   edge = (const int*)d_in[1];
    const float* W    = (const float*)d_in[2];
    const float* bias = (const float*)d_in[3];
    float* out = (float*)d_out;

    int N = in_sizes[0] / CH;   // 100000
    int E = in_sizes[1] / 2;    // 1280000
    const int* src = edge;
    const int* dst = edge + E;
    int R   = (N + RANGE - 1) / RANGE;        // 8
    int NT  = (E + TILE - 1) / TILE;          // 625
    int NB  = (N + BKT - 1) >> BSH;           // 196
    int NPB = (N + 255) / 256;                // 391

    // workspace layout identical to round 16
    int* nspill  = (int*)d_ws;
    int* spill   = nspill + 64;
    int* cnt     = spill + 2 * SPILLMAX;
    int* bucket  = cnt + N;
    unsigned short* partial = (unsigned short*)(bucket + (size_t)N * CAP);
    int* tileHist = (int*)(partial + (size_t)SLICES * R * RANGE);
    int* totals   = tileHist + NT * 256;
    int* sorted   = (int*)partial;            // written by binC (after rpscaleB)
    size_t endoff = (char*)(totals + 320) - (char*)d_ws;
    size_t xoff = (endoff + 255) & ~(size_t)255;
    __half* xh = (__half*)((char*)d_ws + xoff);
    size_t aoff = ((xoff + (size_t)N * CH * sizeof(__half)) + 255) & ~(size_t)255;
    __half* aggh = (__half*)((char*)d_ws + aoff);

    // K1: binA tiles (bid<NT) + outdeg hist (bid>=NT); also zeroes nspill
    histA_kernel<<<NT + R * SLICES, 256, 0, stream>>>(src, dst, partial, tileHist,
                                                      nspill, E, N, R, NT);
    // K2: rpscale (bid<NPB) + binB bucket scans (bid>=NPB)
    rpscaleB_kernel<<<NPB + NB, 256, 0, stream>>>(partial, x, xh, tileHist, totals,
                                                  N, R, NT, NPB);
    binC_kernel<<<NT, 256, 0, stream>>>(src, dst, tileHist, totals, sorted, E, NB);
    binD_kernel<<<NB, 256, 0, stream>>>(sorted, totals, bucket, cnt, spill, nspill, N, NB);
    agg_kernel<<<4096, 256, 0, stream>>>(xh, bucket, cnt, spill, nspill, aggh, N);
    int nwaves = 4 * ((N + 63) / 64);
    gemm_out_kernel<<<(nwaves + 3) / 4, 256, 0, stream>>>(aggh, W, bias, out, N);
}

// Round 18
// 107.901 us; speedup vs baseline: 8.0385x; 1.0102x over previous
//
#include <hip/hip_runtime.h>
#include <hip/hip_fp16.h>

#define CH 64
#define CAP 32        // per-node bucket row = 128B (2 lines); Poisson(12.8) P(>32) ~ 1e-6
#define SPILLMAX 4096
#define HBINS 12500   // LDS ints per hist block; 2 packed u16 counters each = 25000 nodes
#define HSPAN 25000   // nodes covered per hist block
#define SLICES 128    // 4 ranges x 128 slices = 512 hist blocks; 10000 edges/slice < 65535
#define TILE 2048     // edges per binA/binC block
#define EPT 8         // edges per thread (256 * 8 = 2048)
#define BSH 9         // 512 dsts per radix bucket
#define BKT 512

// ---------------- K1: fused binA (tiles) + outdeg hist (ranges) -------------
// hist role: two u16 counters packed per int -> 25000 nodes/block, src read 4x not 8x.
__global__ __launch_bounds__(256) void histA_kernel(const int* __restrict__ src,
                                                    const int* __restrict__ dst,
                                                    int* __restrict__ partial,
                                                    int* __restrict__ tileHist,
                                                    int* __restrict__ nspill,
                                                    int E, int N, int R, int NT)
{
    __shared__ int h[HBINS];
    int tid = threadIdx.x;
    int bid = blockIdx.x;
    if (bid < NT) {
        // ---- binA role ----
        if (bid == 0 && tid == 0) nspill[0] = 0;   // consumed by binD, 3 kernels later
        h[tid] = 0;
        __syncthreads();
        int e0 = bid * TILE + tid * EPT;
        if (e0 + EPT <= E) {
            const int4* dp = (const int4*)(dst + e0);
            int4 a = dp[0], b = dp[1];
            atomicAdd(&h[a.x >> BSH], 1); atomicAdd(&h[a.y >> BSH], 1);
            atomicAdd(&h[a.z >> BSH], 1); atomicAdd(&h[a.w >> BSH], 1);
            atomicAdd(&h[b.x >> BSH], 1); atomicAdd(&h[b.y >> BSH], 1);
            atomicAdd(&h[b.z >> BSH], 1); atomicAdd(&h[b.w >> BSH], 1);
        } else {
            for (int k = e0; k < E && k < e0 + EPT; ++k) atomicAdd(&h[dst[k] >> BSH], 1);
        }
        __syncthreads();
        tileHist[bid * 256 + tid] = h[tid];
    } else {
        // ---- hist role (packed u16 pairs) ----
        int hb = bid - NT;
        int r  = hb % R;
        int sl = hb / R;
        int lo = r * HSPAN;
        int hi = min(lo + HSPAN, N);
        for (int i = tid; i < HBINS; i += 256) h[i] = 0;
        __syncthreads();
        int per = (E + SLICES - 1) / SLICES;
        int sb = sl * per, se = min(sb + per, E);
        for (int e = sb + tid * 4; e < se; e += 256 * 4) {
            if (e + 4 <= se) {
                int4 v = *(const int4*)(src + e);
                if (v.x >= lo && v.x < hi) { int i0 = v.x - lo; atomicAdd(&h[i0 >> 1], 1u << ((i0 & 1) << 4)); }
                if (v.y >= lo && v.y < hi) { int i1 = v.y - lo; atomicAdd(&h[i1 >> 1], 1u << ((i1 & 1) << 4)); }
                if (v.z >= lo && v.z < hi) { int i2 = v.z - lo; atomicAdd(&h[i2 >> 1], 1u << ((i2 & 1) << 4)); }
                if (v.w >= lo && v.w < hi) { int i3 = v.w - lo; atomicAdd(&h[i3 >> 1], 1u << ((i3 & 1) << 4)); }
            } else {
                for (int k = e; k < se; ++k) {
                    int sv = src[k];
                    if (sv >= lo && sv < hi) { int ii = sv - lo; atomicAdd(&h[ii >> 1], 1u << ((ii & 1) << 4)); }
                }
            }
        }
        __syncthreads();
        int* pp = partial + (size_t)hb * HBINS;
        for (int i = tid; i < HBINS; i += 256) pp[i] = h[i];
    }
}

// ---------------- K2: fused rpscale (nodes) + binB (bucket scans) -----------
__global__ __launch_bounds__(256) void rpscaleB_kernel(const int* __restrict__ partial,
                                                       const float* __restrict__ x,
                                                       __half* __restrict__ xh,
                                                       int* __restrict__ tileHist,
                                                       int* __restrict__ totals,
                                                       int N, int R, int NT, int NPB)
{
    __shared__ float nsl[256];
    __shared__ int sm[256];
    int tid = threadIdx.x;
    int bid = blockIdx.x;
    if (bid < NPB) {
        // ---- rpscale role (sum 128 packed-u16 slices per node) ----
        int n0 = bid * 256;
        int n = n0 + tid;
        if (n < N) {
            int r = n / HSPAN;
            int idx = n - r * HSPAN;
            int word = idx >> 1;
            int sh = (idx & 1) << 4;
            int s = 0;
            #pragma unroll 8
            for (int sl = 0; sl < SLICES; ++sl)
                s += (partial[(size_t)(sl * R + r) * HBINS + word] >> sh) & 0xFFFF;
            nsl[tid] = (s > 0) ? rsqrtf((float)s) : 0.0f;
        } else {
            nsl[tid] = 0.0f;
        }
        __syncthreads();
        int sub = tid & 7;
        int nl0 = tid >> 3;
        for (int p = 0; p < 8; ++p) {
            int nl = p * 32 + nl0;
            int node = n0 + nl;
            if (node >= N) break;
            float ns = nsl[nl];
            const float4* xp = (const float4*)(x + (size_t)node * CH + sub * 8);
            float4 a = xp[0], b = xp[1];
            __half2 h0 = __floats2half2_rn(a.x * ns, a.y * ns);
            __half2 h1 = __floats2half2_rn(a.z * ns, a.w * ns);
            __half2 h2 = __floats2half2_rn(b.x * ns, b.y * ns);
            __half2 h3 = __floats2half2_rn(b.z * ns, b.w * ns);
            uint4 u;
            u.x = (unsigned)__half_as_ushort(h0.x) | ((unsigned)__half_as_ushort(h0.y) << 16);
            u.y = (unsigned)__half_as_ushort(h1.x) | ((unsigned)__half_as_ushort(h1.y) << 16);
            u.z = (unsigned)__half_as_ushort(h2.x) | ((unsigned)__half_as_ushort(h2.y) << 16);
            u.w = (unsigned)__half_as_ushort(h3.x) | ((unsigned)__half_as_ushort(h3.y) << 16);
            *(uint4*)(xh + (size_t)node * CH + sub * 8) = u;
        }
    } else {
        // ---- binB role ----
        int b = bid - NPB;
        int C = (NT + 255) / 256;
        int vals[8];
        int s = 0;
        for (int k = 0; k < C; ++k) {
            int t = tid * C + k;
            vals[k] = (t < NT) ? tileHist[t * 256 + b] : 0;
            s += vals[k];
        }
        sm[tid] = s;
        __syncthreads();
        for (int d = 1; d < 256; d <<= 1) {
            int v = (tid >= d) ? sm[tid - d] : 0;
            __syncthreads();
            sm[tid] += v;
            __syncthreads();
        }
        int off = (tid > 0) ? sm[tid - 1] : 0;
        for (int k = 0; k < C; ++k) {
            int t = tid * C + k;
            if (t < NT) { tileHist[t * 256 + b] = off; off += vals[k]; }
        }
        if (tid == 255) totals[b] = sm[255];
    }
}

// ---------------- binC: LDS-staged scatter -> coalesced burst writes --------
__global__ __launch_bounds__(256) void binC_kernel(const int* __restrict__ src,
                                                   const int* __restrict__ dst,
                                                   const int* __restrict__ tileBase,
                                                   const int* __restrict__ totals,
                                                   int* __restrict__ sorted, int E, int NB)
{
    __shared__ int sm[256];     // totals scan -> bucket bases
    __shared__ int gb[256];     // global dest base per bucket for this tile
    __shared__ int lcnt[256];   // block-local per-bucket count / rank cursor
    __shared__ int lbase[256];  // block-local exclusive offsets
    __shared__ int slotVal[TILE];
    int tid = threadIdx.x;
    int t = blockIdx.x;
    sm[tid] = (tid < NB) ? totals[tid] : 0;
    lcnt[tid] = 0;
    __syncthreads();
    for (int d = 1; d < 256; d <<= 1) {
        int v = (tid >= d) ? sm[tid - d] : 0;
        __syncthreads();
        sm[tid] += v;
        __syncthreads();
    }
    int bb = (tid > 0) ? sm[tid - 1] : 0;   // exclusive bucket base
    gb[tid] = (tid < NB) ? bb + tileBase[t * 256 + tid] : 0;
    __syncthreads();
    int e0 = t * TILE + tid * EPT;
    int s[EPT], d[EPT], rk[EPT], pb[EPT];
    int nk = 0;
    if (e0 + EPT <= E) {
        const int4* sp = (const int4*)(src + e0);
        const int4* dp = (const int4*)(dst + e0);
        int4 a = sp[0], b = sp[1], c = dp[0], f = dp[1];
        s[0]=a.x; s[1]=a.y; s[2]=a.z; s[3]=a.w; s[4]=b.x; s[5]=b.y; s[6]=b.z; s[7]=b.w;
        d[0]=c.x; d[1]=c.y; d[2]=c.z; d[3]=c.w; d[4]=f.x; d[5]=f.y; d[6]=f.z; d[7]=f.w;
        nk = EPT;
    } else {
        for (int k = 0; e0 + k < E && k < EPT; ++k) { s[k] = src[e0+k]; d[k] = dst[e0+k]; nk++; }
    }
    for (int k = 0; k < nk; ++k) {
        pb[k] = d[k] >> BSH;
        rk[k] = atomicAdd(&lcnt[pb[k]], 1);
    }
    __syncthreads();
    sm[tid] = lcnt[tid];
    __syncthreads();
    for (int dd = 1; dd < 256; dd <<= 1) {
        int v = (tid >= dd) ? sm[tid - dd] : 0;
        __syncthreads();
        sm[tid] += v;
        __syncthreads();
    }
    lbase[tid] = (tid > 0) ? sm[tid - 1] : 0;
    int total = sm[255];
    __syncthreads();
    for (int k = 0; k < nk; ++k)
        slotVal[lbase[pb[k]] + rk[k]] = (s[k] << BSH) | (d[k] & (BKT - 1));
    __syncthreads();
    for (int i = tid; i < total; i += 256) {
        int lo = 0, hi = 255;            // find largest p with lbase[p] <= i
        #pragma unroll
        for (int st = 0; st < 8; ++st) {
            int mid = (lo + hi + 1) >> 1;
            if (lbase[mid] <= i) lo = mid; else hi = mid - 1;
        }
        sorted[gb[lo] + (i - lbase[lo])] = slotVal[i];
    }
}

// ---------------- binD: bucket-local fill; totals-scan in LDS ---------------
__global__ __launch_bounds__(256) void binD_kernel(const int* __restrict__ sorted,
                                                   const int* __restrict__ totals,
                                                   int* __restrict__ bucket,
                                                   int* __restrict__ cnt,
                                                   int* __restrict__ spill,
                                                   int* __restrict__ nspill, int N, int NB)
{
    __shared__ int sm[256];
    __shared__ int lc[BKT];
    int b = blockIdx.x, tid = threadIdx.x;
    sm[tid] = (tid < NB) ? totals[tid] : 0;
    lc[tid] = 0; lc[tid + 256] = 0;
    __syncthreads();
    for (int d = 1; d < 256; d <<= 1) {
        int v = (tid >= d) ? sm[tid - d] : 0;
        __syncthreads();
        sm[tid] += v;
        __syncthreads();
    }
    int beg = (b > 0) ? sm[b - 1] : 0;
    int end = sm[b];
    int nbase = b << BSH;
    for (int i = beg + tid; i < end; i += 256) {
        int v = sorted[i];
        int sv = v >> BSH;
        int dl = v & (BKT - 1);
        int pos = atomicAdd(&lc[dl], 1);
        if (pos < CAP) {
            bucket[(size_t)(nbase + dl) * CAP + pos] = sv;
        } else {                                  // statistically never
            int sp = atomicAdd(nspill, 1);
            if (sp < SPILLMAX) { spill[2*sp] = nbase + dl; spill[2*sp+1] = sv; }
        }
    }
    __syncthreads();
    int n0 = nbase + tid;
    if (n0 < N) cnt[n0] = lc[tid];
    int n1 = nbase + 256 + tid;
    if (n1 < N) cnt[n1] = lc[256 + tid];
}

// ---------------- aggregate: half-wave (32 lanes) per node (r16 form) -------
__global__ __launch_bounds__(256) void agg_kernel(const __half* __restrict__ xh,
                                                  const int* __restrict__ bucket,
                                                  const int* __restrict__ cnt,
                                                  const int* __restrict__ spill,
                                                  const int* __restrict__ nspill,
                                                  __half* __restrict__ aggh, int N)
{
    int node = (blockIdx.x * blockDim.x + threadIdx.x) >> 5;
    int sl = threadIdx.x & 31;
    if (node >= N) return;
    int c = cnt[node];
    int m = (c < CAP) ? c : CAP;
    const int* bp = bucket + (size_t)node * CAP;
    float ax0 = 0, ay0 = 0, ax1 = 0, ay1 = 0, ax2 = 0, ay2 = 0, ax3 = 0, ay3 = 0;
    int j = 0;
    for (; j + 8 <= m; j += 8) {                 // 8 gathers in flight
        int4 va = *(const int4*)(bp + j);
        int4 vb = *(const int4*)(bp + j + 4);
        float2 f0 = __half22float2(*(const __half2*)(xh + (size_t)va.x * CH + sl * 2));
        float2 f1 = __half22float2(*(const __half2*)(xh + (size_t)va.y * CH + sl * 2));
        float2 f2 = __half22float2(*(const __half2*)(xh + (size_t)va.z * CH + sl * 2));
        float2 f3 = __half22float2(*(const __half2*)(xh + (size_t)va.w * CH + sl * 2));
        float2 f4 = __half22float2(*(const __half2*)(xh + (size_t)vb.x * CH + sl * 2));
        float2 f5 = __half22float2(*(const __half2*)(xh + (size_t)vb.y * CH + sl * 2));
        float2 f6 = __half22float2(*(const __half2*)(xh + (size_t)vb.z * CH + sl * 2));
        float2 f7 = __half22float2(*(const __half2*)(xh + (size_t)vb.w * CH + sl * 2));
        ax0 += f0.x + f4.x; ay0 += f0.y + f4.y;
        ax1 += f1.x + f5.x; ay1 += f1.y + f5.y;
        ax2 += f2.x + f6.x; ay2 += f2.y + f6.y;
        ax3 += f3.x + f7.x; ay3 += f3.y + f7.y;
    }
    for (; j + 4 <= m; j += 4) {
        int4 va = *(const int4*)(bp + j);
        float2 f0 = __half22float2(*(const __half2*)(xh + (size_t)va.x * CH + sl * 2));
        float2 f1 = __half22float2(*(const __half2*)(xh + (size_t)va.y * CH + sl * 2));
        float2 f2 = __half22float2(*(const __half2*)(xh + (size_t)va.z * CH + sl * 2));
        float2 f3 = __half22float2(*(const __half2*)(xh + (size_t)va.w * CH + sl * 2));
        ax0 += f0.x; ay0 += f0.y;
        ax1 += f1.x; ay1 += f1.y;
        ax2 += f2.x; ay2 += f2.y;
        ax3 += f3.x; ay3 += f3.y;
    }
    for (; j < m; ++j) {
        float2 f = __half22float2(*(const __half2*)(xh + (size_t)bp[j] * CH + sl * 2));
        ax0 += f.x; ay0 += f.y;
    }
    if (c > CAP) {   // cold spill sweep
        int ns = *nspill;
        if (ns > SPILLMAX) ns = SPILLMAX;
        for (int i = 0; i < ns; ++i) {
            if (spill[2 * i] == node) {
                float2 f = __half22float2(*(const __half2*)(xh + (size_t)spill[2 * i + 1] * CH + sl * 2));
                ax0 += f.x; ay0 += f.y;
            }
        }
    }
    float nd = (c > 0) ? rsqrtf((float)c) : 0.0f;
    float rx = ((ax0 + ax1) + (ax2 + ax3)) * nd;
    float ry = ((ay0 + ay1) + (ay2 + ay3)) * nd;
    *(__half2*)(aggh + (size_t)node * CH + sl * 2) = __floats2half2_rn(rx, ry);
}

// ---------------- out = aggh @ W + bias -------------------------------------
// Wave = 64 rows x one 16-ch quarter (quarter is wave-uniform -> W/bias s_load).
__global__ __launch_bounds__(256) void gemm_out_kernel(const __half* __restrict__ aggh,
                                                       const float* __restrict__ W,
                                                       const float* __restrict__ bias,
                                                       float* __restrict__ out, int N)
{
    int g = blockIdx.x * 256 + threadIdx.x;
    int waveId = __builtin_amdgcn_readfirstlane(g >> 6);   // wave-uniform by construction
    int lane = threadIdx.x & 63;
    int quarter = waveId & 3;
    int row = ((waveId >> 2) << 6) + lane;
    if (row >= N) return;
    const int cbase = quarter * 16;                         // scalar
    float acc[16];
    #pragma unroll
    for (int i = 0; i < 16; ++i) acc[i] = 0.0f;
    const __half* xp = aggh + (size_t)row * CH;
    for (int k0 = 0; k0 < CH; k0 += 8) {
        uint4 u = *(const uint4*)(xp + k0);                 // 8 halves, one 16B load
        const __half2* hp = (const __half2*)&u;
        float xk[8];
        #pragma unroll
        for (int j = 0; j < 4; ++j) {
            float2 f = __half22float2(hp[j]);
            xk[2 * j] = f.x; xk[2 * j + 1] = f.y;
        }
        #pragma unroll
        for (int kk = 0; kk < 8; ++kk) {
            const float* wrow = W + (k0 + kk) * CH + cbase; // wave-uniform -> s_load
            #pragma unroll
            for (int q = 0; q < 4; ++q) {
                float4 w = *(const float4*)(wrow + q * 4);
                acc[q * 4 + 0] += xk[kk] * w.x;
                acc[q * 4 + 1] += xk[kk] * w.y;
                acc[q * 4 + 2] += xk[kk] * w.z;
                acc[q * 4 + 3] += xk[kk] * w.w;
            }
        }
    }
    float* op = out + (size_t)row * CH + cbase;
    #pragma unroll
    for (int q = 0; q < 4; ++q) {
        float4 b = *(const float4*)(bias + cbase + q * 4);  // wave-uniform
        float4 o;
        o.x = acc[q * 4 + 0] + b.x;
        o.y = acc[q * 4 + 1] + b.y;
        o.z = acc[q * 4 + 2] + b.z;
        o.w = acc[q * 4 + 3] + b.w;
        *(float4*)(op + q * 4) = o;                          // 64B contiguous per lane
    }
}

extern "C" void kernel_launch(void* const* d_in, const int* in_sizes, int n_in,
                              void* d_out, int out_size, void* d_ws, size_t ws_size,
                              hipStream_t stream)
{
    const float* x    = (const float*)d_in[0];
    const int*   edge = (const int*)d_in[1];
    const float* W    = (const float*)d_in[2];
    const float* bias = (const float*)d_in[3];
    float* out = (float*)d_out;

    int N = in_sizes[0] / CH;   // 100000
    int E = in_sizes[1] / 2;    // 1280000
    const int* src = edge;
    const int* dst = edge + E;
    int R   = (N + HSPAN - 1) / HSPAN;        // 4
    int NT  = (E + TILE - 1) / TILE;          // 625
    int NB  = (N + BKT - 1) >> BSH;           // 196
    int NPB = (N + 255) / 256;                // 391

    // workspace (ints 4B):
    // [nspill 64][spill 2*SPILLMAX][cnt N][bucket N*CAP]
    // [partial int R*SLICES*HBINS ~25.6MB — REUSED after rpscaleB as sorted E]
    // [tileHist NT*256][totals 320][align][xh N*CH halves][align][aggh N*CH halves]
    int* nspill  = (int*)d_ws;
    int* spill   = nspill + 64;
    int* cnt     = spill + 2 * SPILLMAX;
    int* bucket  = cnt + N;
    int* partial = bucket + (size_t)N * CAP;
    int* tileHist = partial + (size_t)R * SLICES * HBINS;
    int* totals   = tileHist + NT * 256;
    int* sorted   = partial;                  // written by binC (after rpscaleB)
    size_t endoff = (char*)(totals + 320) - (char*)d_ws;
    size_t xoff = (endoff + 255) & ~(size_t)255;
    __half* xh = (__half*)((char*)d_ws + xoff);
    size_t aoff = ((xoff + (size_t)N * CH * sizeof(__half)) + 255) & ~(size_t)255;
    __half* aggh = (__half*)((char*)d_ws + aoff);

    // K1: binA tiles (bid<NT) + packed-u16 outdeg hist (bid>=NT); zeroes nspill
    histA_kernel<<<NT + R * SLICES, 256, 0, stream>>>(src, dst, partial, tileHist,
                                                      nspill, E, N, R, NT);
    // K2: rpscale (bid<NPB) + binB bucket scans (bid>=NPB)
    rpscaleB_kernel<<<NPB + NB, 256, 0, stream>>>(partial, x, xh, tileHist, totals,
                                                  N, R, NT, NPB);
    binC_kernel<<<NT, 256, 0, stream>>>(src, dst, tileHist, totals, sorted, E, NB);
    binD_kernel<<<NB, 256, 0, stream>>>(sorted, totals, bucket, cnt, spill, nspill, N, NB);
    agg_kernel<<<((size_t)N * 32 + 255) / 256, 256, 0, stream>>>(xh, bucket, cnt, spill,
                                                                 nspill, aggh, N);
    int nwaves = 4 * ((N + 63) / 64);
    gemm_out_kernel<<<(nwaves + 3) / 4, 256, 0, stream>>>(aggh, W, bias, out, N);
}